// Round 18
// baseline (105.798 us; speedup 1.0000x reference)
//
#include <hip/hip_runtime.h>
#include <hip/hip_bf16.h>
#include <math.h>

#define TOK 18432
#define EMB 512
#define NH 8
#define HD_ 64
#define HH 48
#define WW 48

typedef __attribute__((ext_vector_type(8))) __bf16 bf16x8;
typedef __attribute__((ext_vector_type(4))) float  f32x4;
typedef __attribute__((ext_vector_type(8))) unsigned short u16x8;

__device__ __forceinline__ ushort f2bf(float x) {
    __hip_bfloat16 b = __float2bfloat16(x);
    return *(ushort*)&b;
}
__device__ __forceinline__ float bf2f(ushort u) {
    __hip_bfloat16 b = *(__hip_bfloat16*)&u;
    return __bfloat162float(b);
}

// async global->LDS, 16B per lane. LDS dest = wave-uniform base + lane*16 (linear).
__device__ __forceinline__ void gload16(const void* g, void* l) {
    __builtin_amdgcn_global_load_lds((const __attribute__((address_space(1))) void*)g,
                                     (__attribute__((address_space(3))) void*)l,
                                     16, 0, 0);
}

// builtin (NOT inline asm) so the hazard recognizer inserts MFMA->VALU nops.
__device__ __forceinline__ f32x4 mfma_bf16(bf16x8 a, bf16x8 b, f32x4 c) {
    return __builtin_amdgcn_mfma_f32_16x16x32_bf16(a, b, c, 0, 0, 0);
}

// ---------------- merged init: x conv (9216 blk) | w_qkv conv (768) |
// w_out conv (256) | RoPE tables (5). One launch.
__global__ __launch_bounds__(256) void init_misc(const float* __restrict__ x,
                                                 ushort* __restrict__ xhi,
                                                 const float* __restrict__ wq,
                                                 ushort* __restrict__ wqhi,
                                                 const float* __restrict__ wo,
                                                 ushort* __restrict__ wohi,
                                                 float2* __restrict__ tabs) {
    int b = blockIdx.x;
    if (b < 10240) {
        const float* src;
        ushort* dst;
        int i;
        if (b < 9216)      { src = x;  dst = xhi;  i = b * 256 + threadIdx.x; }
        else if (b < 9984) { src = wq; dst = wqhi; i = (b - 9216) * 256 + threadIdx.x; }
        else               { src = wo; dst = wohi; i = (b - 9984) * 256 + threadIdx.x; }
        float4 v = ((const float4*)src)[i];
        ushort4 h = {f2bf(v.x), f2bf(v.y), f2bf(v.z), f2bf(v.w)};
        ((ushort4*)dst)[i] = h;
    } else {
        int idx = (b - 10240) * 256 + threadIdx.x;
        if (idx >= 104 * 10) return;
        int row = idx / 10, j = idx % 10;
        float base = fmaf((float)j, 127.0f / 9.0f, 1.0f) * 3.14159265358979323846f;
        float pos;
        if (row < 8)       pos = fmaf((float)row,        2.0f / 7.0f,  -1.0f);
        else if (row < 56) pos = fmaf((float)(row - 8),  2.0f / 47.0f, -1.0f);
        else               pos = fmaf((float)(row - 56), 2.0f / 47.0f, -1.0f);
        float f = pos * base;
        tabs[idx] = make_float2(cosf(f), sinf(f));
    }
}

// ---------------- fused QKV GEMM (transposed) + RMSnorm + RoPE.
// C^T: A = w_qkv bf16, B = x bf16 (both gload16; 0 conflicts). R18: 4-BUFFER
// rotation, TWO batches in flight (counted vmcnt(8)) -- latency cover = 2
// compute phases + 2 barriers (~300+ cy) vs R17's 1-deep (~150 cy exposed).
// Hazards: WAR -- stage(t+2) writes buf[(t-2)&3]; passing barrier t-1 implies
// all waves finished compute(t-2). WAW period 4. RAW: counted wait + barrier.
// bm FAST; head-major outputs via LDS-transpose epilogue (R13).
__global__ __launch_bounds__(256) void gemm_qkv(const ushort* __restrict__ Ah,
                                                const ushort* __restrict__ Bh,
                                                const float2* __restrict__ tabs,
                                                const float* __restrict__ qnw,
                                                const float* __restrict__ knw,
                                                ushort* __restrict__ qbf,
                                                ushort* __restrict__ kbf,
                                                ushort* __restrict__ vbf) {
    const int K = 512, nM = 12;               // 12 M-tiles (1536/128)
    __shared__ __align__(16) char smem[65536];   // 4 x (8K A + 8K B)
#define AS_(b) ((ushort*)(smem + (b) * 16384))
#define BS_(b) ((ushort*)(smem + (b) * 16384 + 8192))
    int nwg = gridDim.x;
    int bid = blockIdx.x;
    int cpx = nwg >> 3;
    int swz = (bid & 7) * cpx + (bid >> 3);
    int bm = (swz % nM) * 128, bn = (swz / nM) * 128;   // bm fast!
    int tid = threadIdx.x;
    int lane = tid & 63, wave = tid >> 6;
    int wr = wave >> 1, wc = wave & 1;
    int fr = lane & 15, kg = lane >> 4;

    f32x4 acc[4][4];
#pragma unroll
    for (int m = 0; m < 4; ++m)
#pragma unroll
        for (int n = 0; n < 4; ++n) acc[m][n] = (f32x4){0.f, 0.f, 0.f, 0.f};

    // one K-step batch = exactly 4 gloads/thread (A:2, B:2)
    auto stage = [&](int buf, int k0) {
#pragma unroll
        for (int it = 0; it < 2; ++it) {
            int f = it * 256 + tid;
            int row = f >> 2, ch = f & 3;
            int sl = ch ^ ((row >> 1) & 3);
            gload16(Ah + (size_t)(bm + row) * K + k0 + sl * 8, AS_(buf) + f * 8);
            gload16(Bh + (size_t)(bn + row) * K + k0 + sl * 8, BS_(buf) + f * 8);
        }
    };

    int nt = K >> 5;                          // 16 K-steps
    stage(0, 0);
    stage(1, 32);
    int cb = 0;
    int ksw = (kg ^ ((fr >> 1) & 3)) * 8;
    for (int t = 0; t < nt; ++t) {
        if (t + 2 < nt) {
            stage((t + 2) & 3, (t + 2) << 5); // issue 2-ahead (stays in flight)
            asm volatile("s_waitcnt vmcnt(8)" ::: "memory");   // batch t landed
        } else if (t + 1 < nt) {
            asm volatile("s_waitcnt vmcnt(4)" ::: "memory");
        } else {
            asm volatile("s_waitcnt vmcnt(0)" ::: "memory");
        }
        __builtin_amdgcn_s_barrier();         // all waves' current buf landed
        __builtin_amdgcn_sched_barrier(0);
        const ushort* Bc = BS_(cb);
        const ushort* Ac = AS_(cb);
        bf16x8 bh[4];
#pragma unroll
        for (int n = 0; n < 4; ++n)
            bh[n] = *(const bf16x8*)&Bc[(wc * 64 + n * 16 + fr) * 32 + ksw];
#pragma unroll
        for (int m = 0; m < 4; ++m) {
            bf16x8 ah = *(const bf16x8*)&Ac[(wr * 64 + m * 16 + fr) * 32 + ksw];
#pragma unroll
            for (int n = 0; n < 4; ++n)
                acc[m][n] = mfma_bf16(ah, bh[n], acc[m][n]);
        }
        cb = (cb + 1) & 3;
    }
    __syncthreads();   // waves not tail-synced; LDS reused below

    // ---- fused epilogue (staging LDS dead, reuse as transpose buffer)
    int g = (bm >> 6) + wr;
    int type = g % 3;        // 0=q, 1=k, 2=v
    int h = g / 3;
    ushort* obuf = (type == 0) ? qbf : (type == 1) ? kbf : vbf;
    float qsc = (type == 0) ? 0.125f : 1.0f;
    float4 wv[4];
    if (type < 2) {
        const float* wptr = type ? knw : qnw;
#pragma unroll
        for (int m = 0; m < 4; ++m)
            wv[m] = *(const float4*)&wptr[m * 16 + kg * 4];
    }
    char* tb = smem + wave * 5120;            // 32 rows x 160B, wave-private
    size_t obase = (size_t)h * TOK + bn + wc * 64;   // head-major token base

#pragma unroll
    for (int hp = 0; hp < 2; ++hp) {
#pragma unroll
        for (int nn = 0; nn < 2; ++nn) {
            int n = hp * 2 + nn;
            int tk = bn + wc * 64 + n * 16 + fr;
            if (type == 2) {
#pragma unroll
                for (int m = 0; m < 4; ++m) {
                    ushort4 pk = {f2bf(acc[m][n][0]), f2bf(acc[m][n][1]),
                                  f2bf(acc[m][n][2]), f2bf(acc[m][n][3])};
                    *(ushort4*)(tb + (nn * 16 + fr) * 160 + (m * 16 + kg * 4) * 2) = pk;
                }
            } else {
                float s = 0.f;
#pragma unroll
                for (int m = 0; m < 4; ++m)
#pragma unroll
                    for (int i = 0; i < 4; ++i)
                        s = fmaf(acc[m][n][i], acc[m][n][i], s);
                s += __shfl_xor(s, 16);
                s += __shfl_xor(s, 32);
                float inv = rsqrtf(s * (1.0f / 64.0f) + 1e-6f);
                int t = tk / (HH * WW);
                int rem = tk % (HH * WW);
                int xx = rem / WW, yy = rem % WW;
#pragma unroll
                for (int m = 0; m < 4; ++m) {
                    float r[4];
                    const float* wm = (const float*)&wv[m];
#pragma unroll
                    for (int u = 0; u < 2; ++u) {
                        int dc0 = m * 16 + kg * 4 + 2 * u;
                        float xn0 = acc[m][n][2 * u]     * inv * wm[2 * u];
                        float xn1 = acc[m][n][2 * u + 1] * inv * wm[2 * u + 1];
                        if (dc0 < 60) {
                            int p = dc0 >> 1;
                            int tr = (p < 10) ? t * 10 + p
                                   : (p < 20) ? (8 + xx) * 10 + (p - 10)
                                              : (56 + yy) * 10 + (p - 20);
                            float2 cs = tabs[tr];
                            r[2 * u]     = fmaf(xn0, cs.x, -xn1 * cs.y);
                            r[2 * u + 1] = fmaf(xn1, cs.x,  xn0 * cs.y);
                        } else {
                            r[2 * u] = xn0;
                            r[2 * u + 1] = xn1;
                        }
                    }
                    ushort4 pk = {f2bf(r[0] * qsc), f2bf(r[1] * qsc),
                                  f2bf(r[2] * qsc), f2bf(r[3] * qsc)};
                    *(ushort4*)(tb + (nn * 16 + fr) * 160 + (m * 16 + kg * 4) * 2) = pk;
                }
            }
        }
        // readback token-per-row, store 1KB-contiguous per wave instruction.
#pragma unroll
        for (int j = 0; j < 4; ++j) {
            int row = j * 8 + (lane >> 3);            // local token 0..31
            int c16 = (lane & 7) * 16;                // 16B chunk in 128B row
            u16x8 v = *(const u16x8*)(tb + row * 160 + c16);
            size_t tok = obase + hp * 32 + row;
            *(u16x8*)(obuf + tok * 64 + (lane & 7) * 8) = v;
        }
    }
#undef AS_
#undef BS_
}

// ---------------- output GEMM: C = o @ w_out^T (non-transposed, coalesced C).
// Same 4-buffer 2-deep counted-vmcnt pipeline as gemm_qkv.
__global__ __launch_bounds__(256) void gemm_out(const ushort* __restrict__ Ah,
                                                const ushort* __restrict__ Bh,
                                                float* __restrict__ C) {
    const int N = 512, K = 512, nbx = 4;
    __shared__ __align__(16) char smem[65536];
#define AS_(b) ((ushort*)(smem + (b) * 16384))
#define BS_(b) ((ushort*)(smem + (b) * 16384 + 8192))
    int nwg = gridDim.x;
    int bid = blockIdx.x;
    int cpx = nwg >> 3;
    int swz = (bid & 7) * cpx + (bid >> 3);
    int bm = (swz / nbx) * 128, bn = (swz % nbx) * 128;
    int tid = threadIdx.x;
    int lane = tid & 63, wave = tid >> 6;
    int wr = wave >> 1, wc = wave & 1;
    int fr = lane & 15, kg = lane >> 4;

    f32x4 acc[4][4];
#pragma unroll
    for (int m = 0; m < 4; ++m)
#pragma unroll
        for (int n = 0; n < 4; ++n) acc[m][n] = (f32x4){0.f, 0.f, 0.f, 0.f};

    auto stage = [&](int buf, int k0) {
#pragma unroll
        for (int it = 0; it < 2; ++it) {
            int f = it * 256 + tid;
            int row = f >> 2, ch = f & 3;
            int sl = ch ^ ((row >> 1) & 3);
            gload16(Ah + (size_t)(bm + row) * K + k0 + sl * 8, AS_(buf) + f * 8);
            gload16(Bh + (size_t)(bn + row) * K + k0 + sl * 8, BS_(buf) + f * 8);
        }
    };

    int nt = K >> 5;
    stage(0, 0);
    stage(1, 32);
    int cb = 0;
    int ksw = (kg ^ ((fr >> 1) & 3)) * 8;
    for (int t = 0; t < nt; ++t) {
        if (t + 2 < nt) {
            stage((t + 2) & 3, (t + 2) << 5);
            asm volatile("s_waitcnt vmcnt(8)" ::: "memory");
        } else if (t + 1 < nt) {
            asm volatile("s_waitcnt vmcnt(4)" ::: "memory");
        } else {
            asm volatile("s_waitcnt vmcnt(0)" ::: "memory");
        }
        __builtin_amdgcn_s_barrier();
        __builtin_amdgcn_sched_barrier(0);
        const ushort* Bc = BS_(cb);
        const ushort* Ac = AS_(cb);
        bf16x8 bh[4];
#pragma unroll
        for (int n = 0; n < 4; ++n)
            bh[n] = *(const bf16x8*)&Bc[(wc * 64 + n * 16 + fr) * 32 + ksw];
#pragma unroll
        for (int m = 0; m < 4; ++m) {
            bf16x8 ah = *(const bf16x8*)&Ac[(wr * 64 + m * 16 + fr) * 32 + ksw];
#pragma unroll
            for (int n = 0; n < 4; ++n)
                acc[m][n] = mfma_bf16(ah, bh[n], acc[m][n]);
        }
        cb = (cb + 1) & 3;
    }
    // epilogue: no LDS reuse, no barrier needed
#pragma unroll
    for (int m = 0; m < 4; ++m) {
        int row0 = bm + wr * 64 + m * 16 + kg * 4;
#pragma unroll
        for (int n = 0; n < 4; ++n) {
            int col = bn + wc * 64 + n * 16 + fr;
#pragma unroll
            for (int i = 0; i < 4; ++i)
                C[(size_t)(row0 + i) * N + col] = acc[m][n][i];
        }
    }
#undef AS_
#undef BS_
}

// ---------------- MFMA neighborhood attention: swapped operands,
// in-register lane-local masked softmax. Block = (2x2 patch, head).
// q/k/v HEAD-MAJOR [h][TOK][64]; output ohi [tok][512].
__global__ __launch_bounds__(256) void attn_mfma(const ushort* __restrict__ qbf,
                                                 const ushort* __restrict__ kbf,
                                                 const ushort* __restrict__ vbf,
                                                 ushort* __restrict__ ohi) {
    __shared__ __align__(16) char smem[45056];
    constexpr int Q_OFF = 0;       // [32 q][64 d] bf16, 128B rows, slot16 ^= row&7
    constexpr int K_OFF = 4096;    // [128 k][64 d] bf16, 128B rows, slot16 ^= row&7
    constexpr int V_OFF = 20480;   // [64 d][128 k] bf16, 256B rows, slot16 ^= d&7
    constexpr int P_OFF = 36864;   // [32 q][128 k] bf16, 256B rows, slot16 ^= q&7

    int patch = blockIdx.x, head = blockIdx.y;
    int bi = patch / 24, bj = patch % 24;
    int x0 = bi * 2, y0 = bj * 2;
    int ubx = min(max(x0 - 1, 0), 44), uby = min(max(y0 - 1, 0), 44);
    int tid = threadIdx.x, lane = tid & 63, w = tid >> 6;
    int fr = lane & 15, kg = lane >> 4;
    size_t hbase = (size_t)head * TOK;

    // ---- stage Q (1 gload/thread, pre-swizzled source chunk)
    {
        int f = tid;
        int row = f >> 3, sp = f & 7, sl = sp ^ (row & 7);
        int t = row >> 2, px = (row >> 1) & 1, py = row & 1;
        size_t tok = ((size_t)(t * HH + x0 + px)) * WW + (y0 + py);
        gload16(qbf + (hbase + tok) * 64 + sl * 8, smem + Q_OFF + f * 16);
    }
    // ---- stage K (4 gloads/thread)
#pragma unroll
    for (int it = 0; it < 4; ++it) {
        int f = it * 256 + tid;
        int row = f >> 3, sp = f & 7, sl = sp ^ (row & 7);
        int s = row >> 4, ki = (row >> 2) & 3, kj = row & 3;
        size_t tok = ((size_t)(s * HH + ubx + ki)) * WW + (uby + kj);
        gload16(kbf + (hbase + tok) * 64 + sl * 8, smem + K_OFF + f * 16);
    }
    // ---- stage V^T from vbf: register 4x4 transpose, b64 swizzled writes
#pragma unroll
    for (int it = 0; it < 2; ++it) {
        int u = it * 256 + tid;
        int sk = u >> 4, dg = u & 15;
        int s = sk >> 2, ki = sk & 3;
        ushort4 rv[4];
#pragma unroll
        for (int kj = 0; kj < 4; ++kj) {
            size_t tok = ((size_t)(s * HH + ubx + ki)) * WW + (uby + kj);
            rv[kj] = *(const ushort4*)(vbf + (hbase + tok) * 64 + dg * 4);
        }
        const ushort* rr = (const ushort*)rv;   // rr[kj*4 + dd]
#pragma unroll
        for (int dd = 0; dd < 4; ++dd) {
            int d = dg * 4 + dd;
            ushort4 val = {rr[dd], rr[4 + dd], rr[8 + dd], rr[12 + dd]};
            *(ushort4*)(smem + V_OFF + d * 256 + ((sk * 8) ^ ((d & 7) << 4))) = val;
        }
    }
    __syncthreads();

    // ---- QK^T swapped (S^T = K * Q^T) + in-register masked softmax: waves 0,1
    if (w < 2) {
        int q = w * 16 + fr;         // q = t*4 + px*2 + py
        bf16x8 qb[2];
#pragma unroll
        for (int ks = 0; ks < 2; ++ks)
            qb[ks] = *(const bf16x8*)(smem + Q_OFF + q * 128 +
                                      ((ks * 64 + kg * 16) ^ ((fr & 7) << 4)));
        f32x4 sc[8];
#pragma unroll
        for (int m = 0; m < 8; ++m) sc[m] = (f32x4){0.f, 0.f, 0.f, 0.f};
#pragma unroll
        for (int m = 0; m < 8; ++m)
#pragma unroll
            for (int ks = 0; ks < 2; ++ks) {
                bf16x8 a = *(const bf16x8*)(smem + K_OFF + (m * 16 + fr) * 128 +
                                            ((ks * 64 + kg * 16) ^ ((fr & 7) << 4)));
                sc[m] = mfma_bf16(a, qb[ks], sc[m]);
            }
        // lane holds S[k = m*16 + kg*4 + i][q]: s=m, ki=kg, kj=i
        int xq = x0 + ((q >> 1) & 1), yq = y0 + (q & 1);
        int lox = min(max(xq - 1, 0), 45) - ubx;
        int loy = min(max(yq - 1, 0), 45) - uby;
        bool vki = ((unsigned)(kg - lox)) <= 2u;
        float mx = -1e30f;
        if (vki) {
#pragma unroll
            for (int m = 0; m < 8; ++m)
#pragma unroll
                for (int i = 0; i < 4; ++i)
                    if (((unsigned)(i - loy)) <= 2u) mx = fmaxf(mx, sc[m][i]);
        }
        mx = fmaxf(mx, __shfl_xor(mx, 16));
        mx = fmaxf(mx, __shfl_xor(mx, 32));
        float sum = 0.f;
#pragma unroll
        for (int m = 0; m < 8; ++m)
#pragma unroll
            for (int i = 0; i < 4; ++i) {
                bool v = vki && (((unsigned)(i - loy)) <= 2u);
                float e = v ? __expf(sc[m][i] - mx) : 0.f;
                sc[m][i] = e;
                sum += e;
            }
        sum += __shfl_xor(sum, 16);
        sum += __shfl_xor(sum, 32);
        float inv = 1.0f / sum;
#pragma unroll
        for (int m = 0; m < 8; ++m) {
            ushort4 pk = {f2bf(sc[m][0] * inv), f2bf(sc[m][1] * inv),
                          f2bf(sc[m][2] * inv), f2bf(sc[m][3] * inv)};
            *(ushort4*)(smem + P_OFF + q * 256 +
                        ((m * 32 + kg * 8) ^ ((q & 7) << 4))) = pk;
        }
    }
    __syncthreads();

    // ---- PV swapped (out^T = V^T * P^T): wave w owns d-tile w
    f32x4 ov[2];
    ov[0] = (f32x4){0.f, 0.f, 0.f, 0.f};
    ov[1] = (f32x4){0.f, 0.f, 0.f, 0.f};
#pragma unroll
    for (int kb = 0; kb < 4; ++kb) {
        bf16x8 a = *(const bf16x8*)(smem + V_OFF + (w * 16 + fr) * 256 +
                                    ((kb * 64 + kg * 16) ^ ((fr & 7) << 4)));
#pragma unroll
        for (int nt2 = 0; nt2 < 2; ++nt2) {
            bf16x8 b = *(const bf16x8*)(smem + P_OFF + (nt2 * 16 + fr) * 256 +
                                        ((kb * 64 + kg * 16) ^ ((fr & 7) << 4)));
            ov[nt2] = mfma_bf16(a, b, ov[nt2]);
        }
    }
    // ---- epilogue: lane holds out^T[d = w*16+kg*4+i][q = nt2*16+fr]
#pragma unroll
    for (int nt2 = 0; nt2 < 2; ++nt2) {
        int q = nt2 * 16 + fr;
        int t = q >> 2, px = (q >> 1) & 1, py = q & 1;
        size_t tok = ((size_t)(t * HH + x0 + px)) * WW + (y0 + py);
        size_t ob = tok * 512 + head * 64 + w * 16 + kg * 4;
        ushort4 hv = {f2bf(ov[nt2][0]), f2bf(ov[nt2][1]),
                      f2bf(ov[nt2][2]), f2bf(ov[nt2][3])};
        *(ushort4*)&ohi[ob] = hv;
    }
}

extern "C" void kernel_launch(void* const* d_in, const int* in_sizes, int n_in,
                              void* d_out, int out_size, void* d_ws, size_t ws_size,
                              hipStream_t stream) {
    const float* x     = (const float*)d_in[0];
    const float* w_qkv = (const float*)d_in[1];
    const float* w_out = (const float*)d_in[2];
    const float* qnw   = (const float*)d_in[3];
    const float* knw   = (const float*)d_in[4];
    float* out = (float*)d_out;
    char*  ws  = (char*)d_ws;

    const size_t TABS_B = 16384;
    const size_t WQ_B   = (size_t)1536 * 512 * 2;   // 1,572,864
    const size_t WO_B   = (size_t)512 * 512 * 2;    //   524,288

    // ws layout: tabs | wqhi | wohi | qbf | kbf | vbf | ohi  (~77.6 MB)
    float2* tabs = (float2*)ws;
    ushort* wqhi = (ushort*)(ws + TABS_B);
    ushort* wohi = wqhi + (size_t)1536 * 512;
    ushort* qbf  = (ushort*)(ws + TABS_B + WQ_B + WO_B);   // head-major [h][TOK][64]
    ushort* kbf  = qbf + (size_t)TOK * 512;
    ushort* vbf  = kbf + (size_t)TOK * 512;
    ushort* ohi  = vbf + (size_t)TOK * 512;                // [tok][512]

    // d_out: phase 1 = xhi (bf16 x, 37.7 MB); phase 2 = final fp32 out.
    ushort* xhi = (ushort*)d_out;

    init_misc<<<10245, 256, 0, stream>>>(x, xhi, w_qkv, wqhi, w_out, wohi, tabs);

    // fused: qkv^T GEMM (bf16 x from xhi) + rmsnorm + rope -> q/k/v head-major
    gemm_qkv<<<(1536 / 128) * (TOK / 128), 256, 0, stream>>>(
        wqhi, xhi, tabs, qnw, knw, qbf, kbf, vbf);
    attn_mfma<<<dim3(576, NH), 256, 0, stream>>>(qbf, kbf, vbf, ohi);
    // out = o @ w_out^T  (non-transposed, coalesced C writes)
    gemm_out<<<(TOK / 128) * (512 / 128), 256, 0, stream>>>(ohi, wohi, out);
}

// Round 20
// 102.968 us; speedup vs baseline: 1.0275x; 1.0275x over previous
//
#include <hip/hip_runtime.h>
#include <hip/hip_bf16.h>
#include <math.h>

#define TOK 18432
#define EMB 512
#define NH 8
#define HD_ 64
#define HH 48
#define WW 48

typedef __attribute__((ext_vector_type(8))) __bf16 bf16x8;
typedef __attribute__((ext_vector_type(4))) float  f32x4;
typedef __attribute__((ext_vector_type(8))) unsigned short u16x8;

__device__ __forceinline__ ushort f2bf(float x) {
    __hip_bfloat16 b = __float2bfloat16(x);
    return *(ushort*)&b;
}
__device__ __forceinline__ float bf2f(ushort u) {
    __hip_bfloat16 b = *(__hip_bfloat16*)&u;
    return __bfloat162float(b);
}

// async global->LDS, 16B per lane. LDS dest = wave-uniform base + lane*16 (linear).
__device__ __forceinline__ void gload16(const void* g, void* l) {
    __builtin_amdgcn_global_load_lds((const __attribute__((address_space(1))) void*)g,
                                     (__attribute__((address_space(3))) void*)l,
                                     16, 0, 0);
}

// builtin (NOT inline asm) so the hazard recognizer inserts MFMA->VALU nops.
__device__ __forceinline__ f32x4 mfma_bf16(bf16x8 a, bf16x8 b, f32x4 c) {
    return __builtin_amdgcn_mfma_f32_16x16x32_bf16(a, b, c, 0, 0, 0);
}

// ---------------- merged init: x conv (9216 blk) | w_qkv conv (768) |
// w_out conv (256) | RoPE tables (5). One launch.
__global__ __launch_bounds__(256) void init_misc(const float* __restrict__ x,
                                                 ushort* __restrict__ xhi,
                                                 const float* __restrict__ wq,
                                                 ushort* __restrict__ wqhi,
                                                 const float* __restrict__ wo,
                                                 ushort* __restrict__ wohi,
                                                 float2* __restrict__ tabs) {
    int b = blockIdx.x;
    if (b < 10240) {
        const float* src;
        ushort* dst;
        int i;
        if (b < 9216)      { src = x;  dst = xhi;  i = b * 256 + threadIdx.x; }
        else if (b < 9984) { src = wq; dst = wqhi; i = (b - 9216) * 256 + threadIdx.x; }
        else               { src = wo; dst = wohi; i = (b - 9984) * 256 + threadIdx.x; }
        float4 v = ((const float4*)src)[i];
        ushort4 h = {f2bf(v.x), f2bf(v.y), f2bf(v.z), f2bf(v.w)};
        ((ushort4*)dst)[i] = h;
    } else {
        int idx = (b - 10240) * 256 + threadIdx.x;
        if (idx >= 104 * 10) return;
        int row = idx / 10, j = idx % 10;
        float base = fmaf((float)j, 127.0f / 9.0f, 1.0f) * 3.14159265358979323846f;
        float pos;
        if (row < 8)       pos = fmaf((float)row,        2.0f / 7.0f,  -1.0f);
        else if (row < 56) pos = fmaf((float)(row - 8),  2.0f / 47.0f, -1.0f);
        else               pos = fmaf((float)(row - 56), 2.0f / 47.0f, -1.0f);
        float f = pos * base;
        tabs[idx] = make_float2(cosf(f), sinf(f));
    }
}

// ---------------- fused QKV GEMM (transposed) + RMSnorm + RoPE.
// R17 proven config: 3-buffer rotation + raw s_barrier + counted vmcnt(4).
// bm FAST; head-major outputs via LDS-transpose epilogue.
__global__ __launch_bounds__(256) void gemm_qkv(const ushort* __restrict__ Ah,
                                                const ushort* __restrict__ Bh,
                                                const float2* __restrict__ tabs,
                                                const float* __restrict__ qnw,
                                                const float* __restrict__ knw,
                                                ushort* __restrict__ qbf,
                                                ushort* __restrict__ kbf,
                                                ushort* __restrict__ vbf) {
    const int K = 512, nM = 12;               // 12 M-tiles (1536/128)
    __shared__ __align__(16) char smem[49152];   // 3 x (8K A + 8K B)
#define AS_(b) ((ushort*)(smem + (b) * 16384))
#define BS_(b) ((ushort*)(smem + (b) * 16384 + 8192))
    int nwg = gridDim.x;
    int bid = blockIdx.x;
    int cpx = nwg >> 3;
    int swz = (bid & 7) * cpx + (bid >> 3);
    int bm = (swz % nM) * 128, bn = (swz / nM) * 128;   // bm fast!
    int tid = threadIdx.x;
    int lane = tid & 63, wave = tid >> 6;
    int wr = wave >> 1, wc = wave & 1;
    int fr = lane & 15, kg = lane >> 4;

    f32x4 acc[4][4];
#pragma unroll
    for (int m = 0; m < 4; ++m)
#pragma unroll
        for (int n = 0; n < 4; ++n) acc[m][n] = (f32x4){0.f, 0.f, 0.f, 0.f};

    auto stage = [&](int buf, int k0) {
#pragma unroll
        for (int it = 0; it < 2; ++it) {
            int f = it * 256 + tid;
            int row = f >> 2, ch = f & 3;
            int sl = ch ^ ((row >> 1) & 3);
            gload16(Ah + (size_t)(bm + row) * K + k0 + sl * 8, AS_(buf) + f * 8);
            gload16(Bh + (size_t)(bn + row) * K + k0 + sl * 8, BS_(buf) + f * 8);
        }
    };

    int nt = K >> 5;                          // 16 K-steps
    stage(0, 0);
    int cb = 0, nb = 1;
    int ksw = (kg ^ ((fr >> 1) & 3)) * 8;
    for (int t = 0; t < nt; ++t) {
        if (t + 1 < nt) {
            stage(nb, (t + 1) << 5);          // issue next batch (stays in flight)
            asm volatile("s_waitcnt vmcnt(4)" ::: "memory");   // current buf landed
        } else {
            asm volatile("s_waitcnt vmcnt(0)" ::: "memory");
        }
        __builtin_amdgcn_s_barrier();
        __builtin_amdgcn_sched_barrier(0);
        const ushort* Bc = BS_(cb);
        const ushort* Ac = AS_(cb);
        bf16x8 bh[4];
#pragma unroll
        for (int n = 0; n < 4; ++n)
            bh[n] = *(const bf16x8*)&Bc[(wc * 64 + n * 16 + fr) * 32 + ksw];
#pragma unroll
        for (int m = 0; m < 4; ++m) {
            bf16x8 ah = *(const bf16x8*)&Ac[(wr * 64 + m * 16 + fr) * 32 + ksw];
#pragma unroll
            for (int n = 0; n < 4; ++n)
                acc[m][n] = mfma_bf16(ah, bh[n], acc[m][n]);
        }
        cb = (cb + 1 == 3) ? 0 : cb + 1;
        nb = (nb + 1 == 3) ? 0 : nb + 1;
    }
    __syncthreads();   // waves not tail-synced; LDS reused below

    // ---- fused epilogue (staging LDS dead, reuse as transpose buffer)
    int g = (bm >> 6) + wr;
    int type = g % 3;        // 0=q, 1=k, 2=v
    int h = g / 3;
    ushort* obuf = (type == 0) ? qbf : (type == 1) ? kbf : vbf;
    float qsc = (type == 0) ? 0.125f : 1.0f;
    float4 wv[4];
    if (type < 2) {
        const float* wptr = type ? knw : qnw;
#pragma unroll
        for (int m = 0; m < 4; ++m)
            wv[m] = *(const float4*)&wptr[m * 16 + kg * 4];
    }
    char* tb = smem + wave * 5120;            // 32 rows x 160B, wave-private
    size_t obase = (size_t)h * TOK + bn + wc * 64;   // head-major token base

#pragma unroll
    for (int hp = 0; hp < 2; ++hp) {
#pragma unroll
        for (int nn = 0; nn < 2; ++nn) {
            int n = hp * 2 + nn;
            int tk = bn + wc * 64 + n * 16 + fr;
            if (type == 2) {
#pragma unroll
                for (int m = 0; m < 4; ++m) {
                    ushort4 pk = {f2bf(acc[m][n][0]), f2bf(acc[m][n][1]),
                                  f2bf(acc[m][n][2]), f2bf(acc[m][n][3])};
                    *(ushort4*)(tb + (nn * 16 + fr) * 160 + (m * 16 + kg * 4) * 2) = pk;
                }
            } else {
                float s = 0.f;
#pragma unroll
                for (int m = 0; m < 4; ++m)
#pragma unroll
                    for (int i = 0; i < 4; ++i)
                        s = fmaf(acc[m][n][i], acc[m][n][i], s);
                s += __shfl_xor(s, 16);
                s += __shfl_xor(s, 32);
                float inv = rsqrtf(s * (1.0f / 64.0f) + 1e-6f);
                int t = tk / (HH * WW);
                int rem = tk % (HH * WW);
                int xx = rem / WW, yy = rem % WW;
#pragma unroll
                for (int m = 0; m < 4; ++m) {
                    float r[4];
                    const float* wm = (const float*)&wv[m];
#pragma unroll
                    for (int u = 0; u < 2; ++u) {
                        int dc0 = m * 16 + kg * 4 + 2 * u;
                        float xn0 = acc[m][n][2 * u]     * inv * wm[2 * u];
                        float xn1 = acc[m][n][2 * u + 1] * inv * wm[2 * u + 1];
                        if (dc0 < 60) {
                            int p = dc0 >> 1;
                            int tr = (p < 10) ? t * 10 + p
                                   : (p < 20) ? (8 + xx) * 10 + (p - 10)
                                              : (56 + yy) * 10 + (p - 20);
                            float2 cs = tabs[tr];
                            r[2 * u]     = fmaf(xn0, cs.x, -xn1 * cs.y);
                            r[2 * u + 1] = fmaf(xn1, cs.x,  xn0 * cs.y);
                        } else {
                            r[2 * u] = xn0;
                            r[2 * u + 1] = xn1;
                        }
                    }
                    ushort4 pk = {f2bf(r[0] * qsc), f2bf(r[1] * qsc),
                                  f2bf(r[2] * qsc), f2bf(r[3] * qsc)};
                    *(ushort4*)(tb + (nn * 16 + fr) * 160 + (m * 16 + kg * 4) * 2) = pk;
                }
            }
        }
#pragma unroll
        for (int j = 0; j < 4; ++j) {
            int row = j * 8 + (lane >> 3);            // local token 0..31
            int c16 = (lane & 7) * 16;
            u16x8 v = *(const u16x8*)(tb + row * 160 + c16);
            size_t tok = obase + hp * 32 + row;
            *(u16x8*)(obuf + tok * 64 + (lane & 7) * 8) = v;
        }
    }
#undef AS_
#undef BS_
}

// ---------------- output GEMM: C = o @ w_out^T (non-transposed, coalesced C).
// R17 proven 3-buffer counted-vmcnt pipeline.
__global__ __launch_bounds__(256) void gemm_out(const ushort* __restrict__ Ah,
                                                const ushort* __restrict__ Bh,
                                                float* __restrict__ C) {
    const int N = 512, K = 512, nbx = 4;
    __shared__ __align__(16) char smem[49152];
#define AS_(b) ((ushort*)(smem + (b) * 16384))
#define BS_(b) ((ushort*)(smem + (b) * 16384 + 8192))
    int nwg = gridDim.x;
    int bid = blockIdx.x;
    int cpx = nwg >> 3;
    int swz = (bid & 7) * cpx + (bid >> 3);
    int bm = (swz / nbx) * 128, bn = (swz % nbx) * 128;
    int tid = threadIdx.x;
    int lane = tid & 63, wave = tid >> 6;
    int wr = wave >> 1, wc = wave & 1;
    int fr = lane & 15, kg = lane >> 4;

    f32x4 acc[4][4];
#pragma unroll
    for (int m = 0; m < 4; ++m)
#pragma unroll
        for (int n = 0; n < 4; ++n) acc[m][n] = (f32x4){0.f, 0.f, 0.f, 0.f};

    auto stage = [&](int buf, int k0) {
#pragma unroll
        for (int it = 0; it < 2; ++it) {
            int f = it * 256 + tid;
            int row = f >> 2, ch = f & 3;
            int sl = ch ^ ((row >> 1) & 3);
            gload16(Ah + (size_t)(bm + row) * K + k0 + sl * 8, AS_(buf) + f * 8);
            gload16(Bh + (size_t)(bn + row) * K + k0 + sl * 8, BS_(buf) + f * 8);
        }
    };

    int nt = K >> 5;
    stage(0, 0);
    int cb = 0, nb = 1;
    int ksw = (kg ^ ((fr >> 1) & 3)) * 8;
    for (int t = 0; t < nt; ++t) {
        if (t + 1 < nt) {
            stage(nb, (t + 1) << 5);
            asm volatile("s_waitcnt vmcnt(4)" ::: "memory");
        } else {
            asm volatile("s_waitcnt vmcnt(0)" ::: "memory");
        }
        __builtin_amdgcn_s_barrier();
        __builtin_amdgcn_sched_barrier(0);
        const ushort* Bc = BS_(cb);
        const ushort* Ac = AS_(cb);
        bf16x8 bh[4];
#pragma unroll
        for (int n = 0; n < 4; ++n)
            bh[n] = *(const bf16x8*)&Bc[(wc * 64 + n * 16 + fr) * 32 + ksw];
#pragma unroll
        for (int m = 0; m < 4; ++m) {
            bf16x8 ah = *(const bf16x8*)&Ac[(wr * 64 + m * 16 + fr) * 32 + ksw];
#pragma unroll
            for (int n = 0; n < 4; ++n)
                acc[m][n] = mfma_bf16(ah, bh[n], acc[m][n]);
        }
        cb = (cb + 1 == 3) ? 0 : cb + 1;
        nb = (nb + 1 == 3) ? 0 : nb + 1;
    }
#pragma unroll
    for (int m = 0; m < 4; ++m) {
        int row0 = bm + wr * 64 + m * 16 + kg * 4;
#pragma unroll
        for (int n = 0; n < 4; ++n) {
            int col = bn + wc * 64 + n * 16 + fr;
#pragma unroll
            for (int i = 0; i < 4; ++i)
                C[(size_t)(row0 + i) * N + col] = acc[m][n][i];
        }
    }
#undef AS_
#undef BS_
}

// ---------------- MFMA neighborhood attention v4 (fixed): ALL 4 waves in
// QK^T + softmax. Wave w: q-tile qt=w&1, m-half mh=w>>1. Cross-wave
// exchange is PER-Q: XM/XS[qt][mh][16 q], written by kg==0 lanes, combined
// per-lane at index fr (R19 bug: only lane0/q=0's value was exchanged).
// setprio around MFMA clusters. q/k/v HEAD-MAJOR [h][TOK][64].
__global__ __launch_bounds__(256) void attn_mfma(const ushort* __restrict__ qbf,
                                                 const ushort* __restrict__ kbf,
                                                 const ushort* __restrict__ vbf,
                                                 ushort* __restrict__ ohi) {
    __shared__ __align__(16) char smem[45568];
    constexpr int Q_OFF = 0;       // [32 q][64 d] bf16, 128B rows, slot16 ^= row&7
    constexpr int K_OFF = 4096;    // [128 k][64 d] bf16, 128B rows, slot16 ^= row&7
    constexpr int V_OFF = 20480;   // [64 d][128 k] bf16, 256B rows, slot16 ^= d&7
    constexpr int P_OFF = 36864;   // [32 q][128 k] bf16, 256B rows, slot16 ^= q&7
    constexpr int XM_OFF = 45056;  // [2 qt][2 mh][16 q] f32 partial max
    constexpr int XS_OFF = 45312;  // [2 qt][2 mh][16 q] f32 partial sum

    int patch = blockIdx.x, head = blockIdx.y;
    int bi = patch / 24, bj = patch % 24;
    int x0 = bi * 2, y0 = bj * 2;
    int ubx = min(max(x0 - 1, 0), 44), uby = min(max(y0 - 1, 0), 44);
    int tid = threadIdx.x, lane = tid & 63, w = tid >> 6;
    int fr = lane & 15, kg = lane >> 4;
    size_t hbase = (size_t)head * TOK;

    // ---- stage Q (1 gload/thread, pre-swizzled source chunk)
    {
        int f = tid;
        int row = f >> 3, sp = f & 7, sl = sp ^ (row & 7);
        int t = row >> 2, px = (row >> 1) & 1, py = row & 1;
        size_t tok = ((size_t)(t * HH + x0 + px)) * WW + (y0 + py);
        gload16(qbf + (hbase + tok) * 64 + sl * 8, smem + Q_OFF + f * 16);
    }
    // ---- stage K (4 gloads/thread)
#pragma unroll
    for (int it = 0; it < 4; ++it) {
        int f = it * 256 + tid;
        int row = f >> 3, sp = f & 7, sl = sp ^ (row & 7);
        int s = row >> 4, ki = (row >> 2) & 3, kj = row & 3;
        size_t tok = ((size_t)(s * HH + ubx + ki)) * WW + (uby + kj);
        gload16(kbf + (hbase + tok) * 64 + sl * 8, smem + K_OFF + f * 16);
    }
    // ---- stage V^T from vbf: register 4x4 transpose, b64 swizzled writes
#pragma unroll
    for (int it = 0; it < 2; ++it) {
        int u = it * 256 + tid;
        int sk = u >> 4, dg = u & 15;
        int s = sk >> 2, ki = sk & 3;
        ushort4 rv[4];
#pragma unroll
        for (int kj = 0; kj < 4; ++kj) {
            size_t tok = ((size_t)(s * HH + ubx + ki)) * WW + (uby + kj);
            rv[kj] = *(const ushort4*)(vbf + (hbase + tok) * 64 + dg * 4);
        }
        const ushort* rr = (const ushort*)rv;   // rr[kj*4 + dd]
#pragma unroll
        for (int dd = 0; dd < 4; ++dd) {
            int d = dg * 4 + dd;
            ushort4 val = {rr[dd], rr[4 + dd], rr[8 + dd], rr[12 + dd]};
            *(ushort4*)(smem + V_OFF + d * 256 + ((sk * 8) ^ ((d & 7) << 4))) = val;
        }
    }
    __syncthreads();

    // ---- QK^T swapped (S^T = K * Q^T), ALL 4 waves:
    // wave w: q-tile qt = w&1, m-half mh = w>>1 (m = mh*4 .. mh*4+3)
    float* XM = (float*)(smem + XM_OFF);
    float* XS = (float*)(smem + XS_OFF);
    int qt = w & 1, mh = w >> 1;
    int q = qt * 16 + fr;        // q = t*4 + px*2 + py
    {
        bf16x8 qb[2];
#pragma unroll
        for (int ks = 0; ks < 2; ++ks)
            qb[ks] = *(const bf16x8*)(smem + Q_OFF + q * 128 +
                                      ((ks * 64 + kg * 16) ^ ((fr & 7) << 4)));
        f32x4 sc[4];
#pragma unroll
        for (int mm = 0; mm < 4; ++mm) sc[mm] = (f32x4){0.f, 0.f, 0.f, 0.f};
        __builtin_amdgcn_s_setprio(1);
#pragma unroll
        for (int mm = 0; mm < 4; ++mm) {
            int m = mh * 4 + mm;
#pragma unroll
            for (int ks = 0; ks < 2; ++ks) {
                bf16x8 a = *(const bf16x8*)(smem + K_OFF + (m * 16 + fr) * 128 +
                                            ((ks * 64 + kg * 16) ^ ((fr & 7) << 4)));
                sc[mm] = mfma_bf16(a, qb[ks], sc[mm]);
            }
        }
        __builtin_amdgcn_s_setprio(0);
        // lane holds S[k = (mh*4+mm)*16 + kg*4 + i][q]: s=m, ki=kg, kj=i
        int xq = x0 + ((q >> 1) & 1), yq = y0 + (q & 1);
        int lox = min(max(xq - 1, 0), 45) - ubx;
        int loy = min(max(yq - 1, 0), 45) - uby;
        bool vki = ((unsigned)(kg - lox)) <= 2u;
        float mx = -1e30f;
        if (vki) {
#pragma unroll
            for (int mm = 0; mm < 4; ++mm)
#pragma unroll
                for (int i = 0; i < 4; ++i)
                    if (((unsigned)(i - loy)) <= 2u) mx = fmaxf(mx, sc[mm][i]);
        }
        mx = fmaxf(mx, __shfl_xor(mx, 16));   // now per-q (reduced over kg)
        mx = fmaxf(mx, __shfl_xor(mx, 32));
        if (kg == 0) XM[(qt * 2 + mh) * 16 + fr] = mx;
        __syncthreads();
        mx = fmaxf(XM[(qt * 2 + 0) * 16 + fr], XM[(qt * 2 + 1) * 16 + fr]);
        float sum = 0.f;
#pragma unroll
        for (int mm = 0; mm < 4; ++mm)
#pragma unroll
            for (int i = 0; i < 4; ++i) {
                bool v = vki && (((unsigned)(i - loy)) <= 2u);
                float e = v ? __expf(sc[mm][i] - mx) : 0.f;
                sc[mm][i] = e;
                sum += e;
            }
        sum += __shfl_xor(sum, 16);           // per-q partial sum
        sum += __shfl_xor(sum, 32);
        if (kg == 0) XS[(qt * 2 + mh) * 16 + fr] = sum;
        __syncthreads();
        float inv = 1.0f / (XS[(qt * 2 + 0) * 16 + fr] + XS[(qt * 2 + 1) * 16 + fr]);
#pragma unroll
        for (int mm = 0; mm < 4; ++mm) {
            int m = mh * 4 + mm;
            ushort4 pk = {f2bf(sc[mm][0] * inv), f2bf(sc[mm][1] * inv),
                          f2bf(sc[mm][2] * inv), f2bf(sc[mm][3] * inv)};
            *(ushort4*)(smem + P_OFF + q * 256 +
                        ((m * 32 + kg * 8) ^ ((q & 7) << 4))) = pk;
        }
    }
    __syncthreads();

    // ---- PV swapped (out^T = V^T * P^T): wave w owns d-tile w
    f32x4 ov[2];
    ov[0] = (f32x4){0.f, 0.f, 0.f, 0.f};
    ov[1] = (f32x4){0.f, 0.f, 0.f, 0.f};
    __builtin_amdgcn_s_setprio(1);
#pragma unroll
    for (int kb = 0; kb < 4; ++kb) {
        bf16x8 a = *(const bf16x8*)(smem + V_OFF + (w * 16 + fr) * 256 +
                                    ((kb * 64 + kg * 16) ^ ((fr & 7) << 4)));
#pragma unroll
        for (int nt2 = 0; nt2 < 2; ++nt2) {
            bf16x8 b = *(const bf16x8*)(smem + P_OFF + (nt2 * 16 + fr) * 256 +
                                        ((kb * 64 + kg * 16) ^ ((fr & 7) << 4)));
            ov[nt2] = mfma_bf16(a, b, ov[nt2]);
        }
    }
    __builtin_amdgcn_s_setprio(0);
    // ---- epilogue: lane holds out^T[d = w*16+kg*4+i][q = nt2*16+fr]
#pragma unroll
    for (int nt2 = 0; nt2 < 2; ++nt2) {
        int qq = nt2 * 16 + fr;
        int t = qq >> 2, px = (qq >> 1) & 1, py = qq & 1;
        size_t tok = ((size_t)(t * HH + x0 + px)) * WW + (y0 + py);
        size_t ob = tok * 512 + head * 64 + w * 16 + kg * 4;
        ushort4 hv = {f2bf(ov[nt2][0]), f2bf(ov[nt2][1]),
                      f2bf(ov[nt2][2]), f2bf(ov[nt2][3])};
        *(ushort4*)&ohi[ob] = hv;
    }
}

extern "C" void kernel_launch(void* const* d_in, const int* in_sizes, int n_in,
                              void* d_out, int out_size, void* d_ws, size_t ws_size,
                              hipStream_t stream) {
    const float* x     = (const float*)d_in[0];
    const float* w_qkv = (const float*)d_in[1];
    const float* w_out = (const float*)d_in[2];
    const float* qnw   = (const float*)d_in[3];
    const float* knw   = (const float*)d_in[4];
    float* out = (float*)d_out;
    char*  ws  = (char*)d_ws;

    const size_t TABS_B = 16384;
    const size_t WQ_B   = (size_t)1536 * 512 * 2;   // 1,572,864
    const size_t WO_B   = (size_t)512 * 512 * 2;    //   524,288

    // ws layout: tabs | wqhi | wohi | qbf | kbf | vbf | ohi  (~77.6 MB)
    float2* tabs = (float2*)ws;
    ushort* wqhi = (ushort*)(ws + TABS_B);
    ushort* wohi = wqhi + (size_t)1536 * 512;
    ushort* qbf  = (ushort*)(ws + TABS_B + WQ_B + WO_B);   // head-major [h][TOK][64]
    ushort* kbf  = qbf + (size_t)TOK * 512;
    ushort* vbf  = kbf + (size_t)TOK * 512;
    ushort* ohi  = vbf + (size_t)TOK * 512;                // [tok][512]

    // d_out: phase 1 = xhi (bf16 x, 37.7 MB); phase 2 = final fp32 out.
    ushort* xhi = (ushort*)d_out;

    init_misc<<<10245, 256, 0, stream>>>(x, xhi, w_qkv, wqhi, w_out, wohi, tabs);

    // fused: qkv^T GEMM (bf16 x from xhi) + rmsnorm + rope -> q/k/v head-major
    gemm_qkv<<<(1536 / 128) * (TOK / 128), 256, 0, stream>>>(
        wqhi, xhi, tabs, qnw, knw, qbf, kbf, vbf);
    attn_mfma<<<dim3(576, NH), 256, 0, stream>>>(qbf, kbf, vbf, ohi);
    // out = o @ w_out^T  (non-transposed, coalesced C writes)
    gemm_out<<<(TOK / 128) * (512 / 128), 256, 0, stream>>>(ohi, wohi, out);
}

// Round 21
// 101.173 us; speedup vs baseline: 1.0457x; 1.0177x over previous
//
#include <hip/hip_runtime.h>
#include <hip/hip_bf16.h>
#include <math.h>

#define TOK 18432
#define EMB 512
#define NH 8
#define HD_ 64
#define HH 48
#define WW 48

typedef __attribute__((ext_vector_type(8))) __bf16 bf16x8;
typedef __attribute__((ext_vector_type(4))) float  f32x4;
typedef __attribute__((ext_vector_type(8))) unsigned short u16x8;

__device__ __forceinline__ ushort f2bf(float x) {
    __hip_bfloat16 b = __float2bfloat16(x);
    return *(ushort*)&b;
}
__device__ __forceinline__ float bf2f(ushort u) {
    __hip_bfloat16 b = *(__hip_bfloat16*)&u;
    return __bfloat162float(b);
}

// async global->LDS, 16B per lane. LDS dest = wave-uniform base + lane*16 (linear).
__device__ __forceinline__ void gload16(const void* g, void* l) {
    __builtin_amdgcn_global_load_lds((const __attribute__((address_space(1))) void*)g,
                                     (__attribute__((address_space(3))) void*)l,
                                     16, 0, 0);
}

// builtin (NOT inline asm) so the hazard recognizer inserts MFMA->VALU nops.
__device__ __forceinline__ f32x4 mfma_bf16(bf16x8 a, bf16x8 b, f32x4 c) {
    return __builtin_amdgcn_mfma_f32_16x16x32_bf16(a, b, c, 0, 0, 0);
}

// ---------------- merged init: x conv (9216 blk) | w_qkv conv (768) |
// w_out conv (256) | RoPE tables (5). One launch.
__global__ __launch_bounds__(256) void init_misc(const float* __restrict__ x,
                                                 ushort* __restrict__ xhi,
                                                 const float* __restrict__ wq,
                                                 ushort* __restrict__ wqhi,
                                                 const float* __restrict__ wo,
                                                 ushort* __restrict__ wohi,
                                                 float2* __restrict__ tabs) {
    int b = blockIdx.x;
    if (b < 10240) {
        const float* src;
        ushort* dst;
        int i;
        if (b < 9216)      { src = x;  dst = xhi;  i = b * 256 + threadIdx.x; }
        else if (b < 9984) { src = wq; dst = wqhi; i = (b - 9216) * 256 + threadIdx.x; }
        else               { src = wo; dst = wohi; i = (b - 9984) * 256 + threadIdx.x; }
        float4 v = ((const float4*)src)[i];
        ushort4 h = {f2bf(v.x), f2bf(v.y), f2bf(v.z), f2bf(v.w)};
        ((ushort4*)dst)[i] = h;
    } else {
        int idx = (b - 10240) * 256 + threadIdx.x;
        if (idx >= 104 * 10) return;
        int row = idx / 10, j = idx % 10;
        float base = fmaf((float)j, 127.0f / 9.0f, 1.0f) * 3.14159265358979323846f;
        float pos;
        if (row < 8)       pos = fmaf((float)row,        2.0f / 7.0f,  -1.0f);
        else if (row < 56) pos = fmaf((float)(row - 8),  2.0f / 47.0f, -1.0f);
        else               pos = fmaf((float)(row - 56), 2.0f / 47.0f, -1.0f);
        float f = pos * base;
        tabs[idx] = make_float2(cosf(f), sinf(f));
    }
}

// ---------------- fused QKV GEMM (transposed) + RMSnorm + RoPE.
// R21: 512 THREADS (8 waves, 2x4 wave grid, acc[4][2]) on the SAME 128x128
// tile + 48KB 3-buffer counted-vmcnt pipeline -> 24 waves/CU (was 12).
// Per-output-element K-order unchanged (bitwise-identical result).
// bm FAST; head-major outputs via single-pass LDS-transpose epilogue.
__global__ __launch_bounds__(512) void gemm_qkv(const ushort* __restrict__ Ah,
                                                const ushort* __restrict__ Bh,
                                                const float2* __restrict__ tabs,
                                                const float* __restrict__ qnw,
                                                const float* __restrict__ knw,
                                                ushort* __restrict__ qbf,
                                                ushort* __restrict__ kbf,
                                                ushort* __restrict__ vbf) {
    const int K = 512, nM = 12;               // 12 M-tiles (1536/128)
    __shared__ __align__(16) char smem[49152];   // 3 x (8K A + 8K B)
#define AS_(b) ((ushort*)(smem + (b) * 16384))
#define BS_(b) ((ushort*)(smem + (b) * 16384 + 8192))
    int nwg = gridDim.x;
    int bid = blockIdx.x;
    int cpx = nwg >> 3;
    int swz = (bid & 7) * cpx + (bid >> 3);
    int bm = (swz % nM) * 128, bn = (swz / nM) * 128;   // bm fast!
    int tid = threadIdx.x;
    int lane = tid & 63, wave = tid >> 6;     // 8 waves
    int wr = wave >> 2, wc = wave & 3;        // 2 x 4 wave grid
    int fr = lane & 15, kg = lane >> 4;

    f32x4 acc[4][2];
#pragma unroll
    for (int m = 0; m < 4; ++m)
#pragma unroll
        for (int n = 0; n < 2; ++n) acc[m][n] = (f32x4){0.f, 0.f, 0.f, 0.f};

    // one K-step batch = exactly 2 gloads/thread (A:1, B:1); 512 chunks each
    auto stage = [&](int buf, int k0) {
        int row = tid >> 2, ch = tid & 3;
        int sl = ch ^ ((row >> 1) & 3);
        gload16(Ah + (size_t)(bm + row) * K + k0 + sl * 8, AS_(buf) + tid * 8);
        gload16(Bh + (size_t)(bn + row) * K + k0 + sl * 8, BS_(buf) + tid * 8);
    };

    int nt = K >> 5;                          // 16 K-steps
    stage(0, 0);
    int cb = 0, nb = 1;
    int ksw = (kg ^ ((fr >> 1) & 3)) * 8;
    for (int t = 0; t < nt; ++t) {
        if (t + 1 < nt) {
            stage(nb, (t + 1) << 5);          // issue next batch (stays in flight)
            asm volatile("s_waitcnt vmcnt(2)" ::: "memory");   // current buf landed
        } else {
            asm volatile("s_waitcnt vmcnt(0)" ::: "memory");
        }
        __builtin_amdgcn_s_barrier();
        __builtin_amdgcn_sched_barrier(0);
        const ushort* Bc = BS_(cb);
        const ushort* Ac = AS_(cb);
        bf16x8 bh[2];
#pragma unroll
        for (int n = 0; n < 2; ++n)
            bh[n] = *(const bf16x8*)&Bc[(wc * 32 + n * 16 + fr) * 32 + ksw];
#pragma unroll
        for (int m = 0; m < 4; ++m) {
            bf16x8 ah = *(const bf16x8*)&Ac[(wr * 64 + m * 16 + fr) * 32 + ksw];
#pragma unroll
            for (int n = 0; n < 2; ++n)
                acc[m][n] = mfma_bf16(ah, bh[n], acc[m][n]);
        }
        cb = (cb + 1 == 3) ? 0 : cb + 1;
        nb = (nb + 1 == 3) ? 0 : nb + 1;
    }
    __syncthreads();   // waves not tail-synced; LDS reused below

    // ---- fused epilogue (staging LDS dead; wave-private 5KB transpose buf)
    int g = (bm >> 6) + wr;
    int type = g % 3;        // 0=q, 1=k, 2=v
    int h = g / 3;
    ushort* obuf = (type == 0) ? qbf : (type == 1) ? kbf : vbf;
    float qsc = (type == 0) ? 0.125f : 1.0f;
    float4 wv[4];
    if (type < 2) {
        const float* wptr = type ? knw : qnw;
#pragma unroll
        for (int m = 0; m < 4; ++m)
            wv[m] = *(const float4*)&wptr[m * 16 + kg * 4];
    }
    char* tb = smem + wave * 5120;            // 32 rows x 160B, wave-private
    size_t obase = (size_t)h * TOK + bn + wc * 32;   // head-major token base

#pragma unroll
    for (int n = 0; n < 2; ++n) {
        int tk = bn + wc * 32 + n * 16 + fr;
        if (type == 2) {
#pragma unroll
            for (int m = 0; m < 4; ++m) {
                ushort4 pk = {f2bf(acc[m][n][0]), f2bf(acc[m][n][1]),
                              f2bf(acc[m][n][2]), f2bf(acc[m][n][3])};
                *(ushort4*)(tb + (n * 16 + fr) * 160 + (m * 16 + kg * 4) * 2) = pk;
            }
        } else {
            float s = 0.f;
#pragma unroll
            for (int m = 0; m < 4; ++m)
#pragma unroll
                for (int i = 0; i < 4; ++i)
                    s = fmaf(acc[m][n][i], acc[m][n][i], s);
            s += __shfl_xor(s, 16);
            s += __shfl_xor(s, 32);
            float inv = rsqrtf(s * (1.0f / 64.0f) + 1e-6f);
            int t = tk / (HH * WW);
            int rem = tk % (HH * WW);
            int xx = rem / WW, yy = rem % WW;
#pragma unroll
            for (int m = 0; m < 4; ++m) {
                float r[4];
                const float* wm = (const float*)&wv[m];
#pragma unroll
                for (int u = 0; u < 2; ++u) {
                    int dc0 = m * 16 + kg * 4 + 2 * u;
                    float xn0 = acc[m][n][2 * u]     * inv * wm[2 * u];
                    float xn1 = acc[m][n][2 * u + 1] * inv * wm[2 * u + 1];
                    if (dc0 < 60) {
                        int p = dc0 >> 1;
                        int tr = (p < 10) ? t * 10 + p
                               : (p < 20) ? (8 + xx) * 10 + (p - 10)
                                          : (56 + yy) * 10 + (p - 20);
                        float2 cs = tabs[tr];
                        r[2 * u]     = fmaf(xn0, cs.x, -xn1 * cs.y);
                        r[2 * u + 1] = fmaf(xn1, cs.x,  xn0 * cs.y);
                    } else {
                        r[2 * u] = xn0;
                        r[2 * u + 1] = xn1;
                    }
                }
                ushort4 pk = {f2bf(r[0] * qsc), f2bf(r[1] * qsc),
                              f2bf(r[2] * qsc), f2bf(r[3] * qsc)};
                *(ushort4*)(tb + (n * 16 + fr) * 160 + (m * 16 + kg * 4) * 2) = pk;
            }
        }
    }
    // readback token-per-row, store 1KB-contiguous per wave instruction.
#pragma unroll
    for (int j = 0; j < 4; ++j) {
        int row = j * 8 + (lane >> 3);            // local token 0..31
        int c16 = (lane & 7) * 16;                // 16B chunk in 128B row
        u16x8 v = *(const u16x8*)(tb + row * 160 + c16);
        size_t tok = obase + row;
        *(u16x8*)(obuf + tok * 64 + (lane & 7) * 8) = v;
    }
#undef AS_
#undef BS_
}

// ---------------- output GEMM: C = o @ w_out^T (non-transposed, coalesced C).
// R21: 512 threads, 128x128 tile, 3-buffer counted-vmcnt(2) pipeline.
__global__ __launch_bounds__(512) void gemm_out(const ushort* __restrict__ Ah,
                                                const ushort* __restrict__ Bh,
                                                float* __restrict__ C) {
    const int N = 512, K = 512, nbx = 4;
    __shared__ __align__(16) char smem[49152];
#define AS_(b) ((ushort*)(smem + (b) * 16384))
#define BS_(b) ((ushort*)(smem + (b) * 16384 + 8192))
    int nwg = gridDim.x;
    int bid = blockIdx.x;
    int cpx = nwg >> 3;
    int swz = (bid & 7) * cpx + (bid >> 3);
    int bm = (swz / nbx) * 128, bn = (swz % nbx) * 128;
    int tid = threadIdx.x;
    int lane = tid & 63, wave = tid >> 6;
    int wr = wave >> 2, wc = wave & 3;
    int fr = lane & 15, kg = lane >> 4;

    f32x4 acc[4][2];
#pragma unroll
    for (int m = 0; m < 4; ++m)
#pragma unroll
        for (int n = 0; n < 2; ++n) acc[m][n] = (f32x4){0.f, 0.f, 0.f, 0.f};

    auto stage = [&](int buf, int k0) {
        int row = tid >> 2, ch = tid & 3;
        int sl = ch ^ ((row >> 1) & 3);
        gload16(Ah + (size_t)(bm + row) * K + k0 + sl * 8, AS_(buf) + tid * 8);
        gload16(Bh + (size_t)(bn + row) * K + k0 + sl * 8, BS_(buf) + tid * 8);
    };

    int nt = K >> 5;
    stage(0, 0);
    int cb = 0, nb = 1;
    int ksw = (kg ^ ((fr >> 1) & 3)) * 8;
    for (int t = 0; t < nt; ++t) {
        if (t + 1 < nt) {
            stage(nb, (t + 1) << 5);
            asm volatile("s_waitcnt vmcnt(2)" ::: "memory");
        } else {
            asm volatile("s_waitcnt vmcnt(0)" ::: "memory");
        }
        __builtin_amdgcn_s_barrier();
        __builtin_amdgcn_sched_barrier(0);
        const ushort* Bc = BS_(cb);
        const ushort* Ac = AS_(cb);
        bf16x8 bh[2];
#pragma unroll
        for (int n = 0; n < 2; ++n)
            bh[n] = *(const bf16x8*)&Bc[(wc * 32 + n * 16 + fr) * 32 + ksw];
#pragma unroll
        for (int m = 0; m < 4; ++m) {
            bf16x8 ah = *(const bf16x8*)&Ac[(wr * 64 + m * 16 + fr) * 32 + ksw];
#pragma unroll
            for (int n = 0; n < 2; ++n)
                acc[m][n] = mfma_bf16(ah, bh[n], acc[m][n]);
        }
        cb = (cb + 1 == 3) ? 0 : cb + 1;
        nb = (nb + 1 == 3) ? 0 : nb + 1;
    }
#pragma unroll
    for (int m = 0; m < 4; ++m) {
        int row0 = bm + wr * 64 + m * 16 + kg * 4;
#pragma unroll
        for (int n = 0; n < 2; ++n) {
            int col = bn + wc * 32 + n * 16 + fr;
#pragma unroll
            for (int i = 0; i < 4; ++i)
                C[(size_t)(row0 + i) * N + col] = acc[m][n][i];
        }
    }
#undef AS_
#undef BS_
}

// ---------------- MFMA neighborhood attention v4: ALL 4 waves in QK^T +
// softmax, per-q cross-wave exchange, setprio. Block = (2x2 patch, head).
// q/k/v HEAD-MAJOR [h][TOK][64]; output ohi [tok][512].
__global__ __launch_bounds__(256) void attn_mfma(const ushort* __restrict__ qbf,
                                                 const ushort* __restrict__ kbf,
                                                 const ushort* __restrict__ vbf,
                                                 ushort* __restrict__ ohi) {
    __shared__ __align__(16) char smem[45568];
    constexpr int Q_OFF = 0;       // [32 q][64 d] bf16, 128B rows, slot16 ^= row&7
    constexpr int K_OFF = 4096;    // [128 k][64 d] bf16, 128B rows, slot16 ^= row&7
    constexpr int V_OFF = 20480;   // [64 d][128 k] bf16, 256B rows, slot16 ^= d&7
    constexpr int P_OFF = 36864;   // [32 q][128 k] bf16, 256B rows, slot16 ^= q&7
    constexpr int XM_OFF = 45056;  // [2 qt][2 mh][16 q] f32 partial max
    constexpr int XS_OFF = 45312;  // [2 qt][2 mh][16 q] f32 partial sum

    int patch = blockIdx.x, head = blockIdx.y;
    int bi = patch / 24, bj = patch % 24;
    int x0 = bi * 2, y0 = bj * 2;
    int ubx = min(max(x0 - 1, 0), 44), uby = min(max(y0 - 1, 0), 44);
    int tid = threadIdx.x, lane = tid & 63, w = tid >> 6;
    int fr = lane & 15, kg = lane >> 4;
    size_t hbase = (size_t)head * TOK;

    // ---- stage Q (1 gload/thread, pre-swizzled source chunk)
    {
        int f = tid;
        int row = f >> 3, sp = f & 7, sl = sp ^ (row & 7);
        int t = row >> 2, px = (row >> 1) & 1, py = row & 1;
        size_t tok = ((size_t)(t * HH + x0 + px)) * WW + (y0 + py);
        gload16(qbf + (hbase + tok) * 64 + sl * 8, smem + Q_OFF + f * 16);
    }
    // ---- stage K (4 gloads/thread)
#pragma unroll
    for (int it = 0; it < 4; ++it) {
        int f = it * 256 + tid;
        int row = f >> 3, sp = f & 7, sl = sp ^ (row & 7);
        int s = row >> 4, ki = (row >> 2) & 3, kj = row & 3;
        size_t tok = ((size_t)(s * HH + ubx + ki)) * WW + (uby + kj);
        gload16(kbf + (hbase + tok) * 64 + sl * 8, smem + K_OFF + f * 16);
    }
    // ---- stage V^T from vbf: register 4x4 transpose, b64 swizzled writes
#pragma unroll
    for (int it = 0; it < 2; ++it) {
        int u = it * 256 + tid;
        int sk = u >> 4, dg = u & 15;
        int s = sk >> 2, ki = sk & 3;
        ushort4 rv[4];
#pragma unroll
        for (int kj = 0; kj < 4; ++kj) {
            size_t tok = ((size_t)(s * HH + ubx + ki)) * WW + (uby + kj);
            rv[kj] = *(const ushort4*)(vbf + (hbase + tok) * 64 + dg * 4);
        }
        const ushort* rr = (const ushort*)rv;   // rr[kj*4 + dd]
#pragma unroll
        for (int dd = 0; dd < 4; ++dd) {
            int d = dg * 4 + dd;
            ushort4 val = {rr[dd], rr[4 + dd], rr[8 + dd], rr[12 + dd]};
            *(ushort4*)(smem + V_OFF + d * 256 + ((sk * 8) ^ ((d & 7) << 4))) = val;
        }
    }
    __syncthreads();

    // ---- QK^T swapped (S^T = K * Q^T), ALL 4 waves:
    // wave w: q-tile qt = w&1, m-half mh = w>>1 (m = mh*4 .. mh*4+3)
    float* XM = (float*)(smem + XM_OFF);
    float* XS = (float*)(smem + XS_OFF);
    int qt = w & 1, mh = w >> 1;
    int q = qt * 16 + fr;        // q = t*4 + px*2 + py
    {
        bf16x8 qb[2];
#pragma unroll
        for (int ks = 0; ks < 2; ++ks)
            qb[ks] = *(const bf16x8*)(smem + Q_OFF + q * 128 +
                                      ((ks * 64 + kg * 16) ^ ((fr & 7) << 4)));
        f32x4 sc[4];
#pragma unroll
        for (int mm = 0; mm < 4; ++mm) sc[mm] = (f32x4){0.f, 0.f, 0.f, 0.f};
        __builtin_amdgcn_s_setprio(1);
#pragma unroll
        for (int mm = 0; mm < 4; ++mm) {
            int m = mh * 4 + mm;
#pragma unroll
            for (int ks = 0; ks < 2; ++ks) {
                bf16x8 a = *(const bf16x8*)(smem + K_OFF + (m * 16 + fr) * 128 +
                                            ((ks * 64 + kg * 16) ^ ((fr & 7) << 4)));
                sc[mm] = mfma_bf16(a, qb[ks], sc[mm]);
            }
        }
        __builtin_amdgcn_s_setprio(0);
        // lane holds S[k = (mh*4+mm)*16 + kg*4 + i][q]: s=m, ki=kg, kj=i
        int xq = x0 + ((q >> 1) & 1), yq = y0 + (q & 1);
        int lox = min(max(xq - 1, 0), 45) - ubx;
        int loy = min(max(yq - 1, 0), 45) - uby;
        bool vki = ((unsigned)(kg - lox)) <= 2u;
        float mx = -1e30f;
        if (vki) {
#pragma unroll
            for (int mm = 0; mm < 4; ++mm)
#pragma unroll
                for (int i = 0; i < 4; ++i)
                    if (((unsigned)(i - loy)) <= 2u) mx = fmaxf(mx, sc[mm][i]);
        }
        mx = fmaxf(mx, __shfl_xor(mx, 16));   // per-q (reduced over kg)
        mx = fmaxf(mx, __shfl_xor(mx, 32));
        if (kg == 0) XM[(qt * 2 + mh) * 16 + fr] = mx;
        __syncthreads();
        mx = fmaxf(XM[(qt * 2 + 0) * 16 + fr], XM[(qt * 2 + 1) * 16 + fr]);
        float sum = 0.f;
#pragma unroll
        for (int mm = 0; mm < 4; ++mm)
#pragma unroll
            for (int i = 0; i < 4; ++i) {
                bool v = vki && (((unsigned)(i - loy)) <= 2u);
                float e = v ? __expf(sc[mm][i] - mx) : 0.f;
                sc[mm][i] = e;
                sum += e;
            }
        sum += __shfl_xor(sum, 16);           // per-q partial sum
        sum += __shfl_xor(sum, 32);
        if (kg == 0) XS[(qt * 2 + mh) * 16 + fr] = sum;
        __syncthreads();
        float inv = 1.0f / (XS[(qt * 2 + 0) * 16 + fr] + XS[(qt * 2 + 1) * 16 + fr]);
#pragma unroll
        for (int mm = 0; mm < 4; ++mm) {
            int m = mh * 4 + mm;
            ushort4 pk = {f2bf(sc[mm][0] * inv), f2bf(sc[mm][1] * inv),
                          f2bf(sc[mm][2] * inv), f2bf(sc[mm][3] * inv)};
            *(ushort4*)(smem + P_OFF + q * 256 +
                        ((m * 32 + kg * 8) ^ ((q & 7) << 4))) = pk;
        }
    }
    __syncthreads();

    // ---- PV swapped (out^T = V^T * P^T): wave w owns d-tile w
    f32x4 ov[2];
    ov[0] = (f32x4){0.f, 0.f, 0.f, 0.f};
    ov[1] = (f32x4){0.f, 0.f, 0.f, 0.f};
    __builtin_amdgcn_s_setprio(1);
#pragma unroll
    for (int kb = 0; kb < 4; ++kb) {
        bf16x8 a = *(const bf16x8*)(smem + V_OFF + (w * 16 + fr) * 256 +
                                    ((kb * 64 + kg * 16) ^ ((fr & 7) << 4)));
#pragma unroll
        for (int nt2 = 0; nt2 < 2; ++nt2) {
            bf16x8 b = *(const bf16x8*)(smem + P_OFF + (nt2 * 16 + fr) * 256 +
                                        ((kb * 64 + kg * 16) ^ ((fr & 7) << 4)));
            ov[nt2] = mfma_bf16(a, b, ov[nt2]);
        }
    }
    __builtin_amdgcn_s_setprio(0);
    // ---- epilogue: lane holds out^T[d = w*16+kg*4+i][q = nt2*16+fr]
#pragma unroll
    for (int nt2 = 0; nt2 < 2; ++nt2) {
        int qq = nt2 * 16 + fr;
        int t = qq >> 2, px = (qq >> 1) & 1, py = qq & 1;
        size_t tok = ((size_t)(t * HH + x0 + px)) * WW + (y0 + py);
        size_t ob = tok * 512 + head * 64 + w * 16 + kg * 4;
        ushort4 hv = {f2bf(ov[nt2][0]), f2bf(ov[nt2][1]),
                      f2bf(ov[nt2][2]), f2bf(ov[nt2][3])};
        *(ushort4*)&ohi[ob] = hv;
    }
}

extern "C" void kernel_launch(void* const* d_in, const int* in_sizes, int n_in,
                              void* d_out, int out_size, void* d_ws, size_t ws_size,
                              hipStream_t stream) {
    const float* x     = (const float*)d_in[0];
    const float* w_qkv = (const float*)d_in[1];
    const float* w_out = (const float*)d_in[2];
    const float* qnw   = (const float*)d_in[3];
    const float* knw   = (const float*)d_in[4];
    float* out = (float*)d_out;
    char*  ws  = (char*)d_ws;

    const size_t TABS_B = 16384;
    const size_t WQ_B   = (size_t)1536 * 512 * 2;   // 1,572,864
    const size_t WO_B   = (size_t)512 * 512 * 2;    //   524,288

    // ws layout: tabs | wqhi | wohi | qbf | kbf | vbf | ohi  (~77.6 MB)
    float2* tabs = (float2*)ws;
    ushort* wqhi = (ushort*)(ws + TABS_B);
    ushort* wohi = wqhi + (size_t)1536 * 512;
    ushort* qbf  = (ushort*)(ws + TABS_B + WQ_B + WO_B);   // head-major [h][TOK][64]
    ushort* kbf  = qbf + (size_t)TOK * 512;
    ushort* vbf  = kbf + (size_t)TOK * 512;
    ushort* ohi  = vbf + (size_t)TOK * 512;                // [tok][512]

    // d_out: phase 1 = xhi (bf16 x, 37.7 MB); phase 2 = final fp32 out.
    ushort* xhi = (ushort*)d_out;

    init_misc<<<10245, 256, 0, stream>>>(x, xhi, w_qkv, wqhi, w_out, wohi, tabs);

    // fused: qkv^T GEMM (bf16 x from xhi) + rmsnorm + rope -> q/k/v head-major
    gemm_qkv<<<(1536 / 128) * (TOK / 128), 512, 0, stream>>>(
        wqhi, xhi, tabs, qnw, knw, qbf, kbf, vbf);
    attn_mfma<<<dim3(576, NH), 256, 0, stream>>>(qbf, kbf, vbf, ohi);
    // out = o @ w_out^T  (non-transposed, coalesced C writes)
    gemm_out<<<(TOK / 128) * (512 / 128), 512, 0, stream>>>(ohi, wohi, out);
}

// Round 22
// 100.603 us; speedup vs baseline: 1.0516x; 1.0057x over previous
//
#include <hip/hip_runtime.h>
#include <hip/hip_bf16.h>
#include <math.h>

#define TOK 18432
#define EMB 512
#define NH 8
#define HD_ 64
#define HH 48
#define WW 48

typedef __attribute__((ext_vector_type(8))) __bf16 bf16x8;
typedef __attribute__((ext_vector_type(4))) float  f32x4;
typedef __attribute__((ext_vector_type(8))) unsigned short u16x8;

__device__ __forceinline__ ushort f2bf(float x) {
    __hip_bfloat16 b = __float2bfloat16(x);
    return *(ushort*)&b;
}
__device__ __forceinline__ float bf2f(ushort u) {
    __hip_bfloat16 b = *(__hip_bfloat16*)&u;
    return __bfloat162float(b);
}

// async global->LDS, 16B per lane. LDS dest = wave-uniform base + lane*16 (linear).
__device__ __forceinline__ void gload16(const void* g, void* l) {
    __builtin_amdgcn_global_load_lds((const __attribute__((address_space(1))) void*)g,
                                     (__attribute__((address_space(3))) void*)l,
                                     16, 0, 0);
}

// builtin (NOT inline asm) so the hazard recognizer inserts MFMA->VALU nops.
__device__ __forceinline__ f32x4 mfma_bf16(bf16x8 a, bf16x8 b, f32x4 c) {
    return __builtin_amdgcn_mfma_f32_16x16x32_bf16(a, b, c, 0, 0, 0);
}

// ---------------- merged init: x conv (9216 blk) | w_qkv conv (768) |
// w_out conv (256) | RoPE tables (5). One launch.
__global__ __launch_bounds__(256) void init_misc(const float* __restrict__ x,
                                                 ushort* __restrict__ xhi,
                                                 const float* __restrict__ wq,
                                                 ushort* __restrict__ wqhi,
                                                 const float* __restrict__ wo,
                                                 ushort* __restrict__ wohi,
                                                 float2* __restrict__ tabs) {
    int b = blockIdx.x;
    if (b < 10240) {
        const float* src;
        ushort* dst;
        int i;
        if (b < 9216)      { src = x;  dst = xhi;  i = b * 256 + threadIdx.x; }
        else if (b < 9984) { src = wq; dst = wqhi; i = (b - 9216) * 256 + threadIdx.x; }
        else               { src = wo; dst = wohi; i = (b - 9984) * 256 + threadIdx.x; }
        float4 v = ((const float4*)src)[i];
        ushort4 h = {f2bf(v.x), f2bf(v.y), f2bf(v.z), f2bf(v.w)};
        ((ushort4*)dst)[i] = h;
    } else {
        int idx = (b - 10240) * 256 + threadIdx.x;
        if (idx >= 104 * 10) return;
        int row = idx / 10, j = idx % 10;
        float base = fmaf((float)j, 127.0f / 9.0f, 1.0f) * 3.14159265358979323846f;
        float pos;
        if (row < 8)       pos = fmaf((float)row,        2.0f / 7.0f,  -1.0f);
        else if (row < 56) pos = fmaf((float)(row - 8),  2.0f / 47.0f, -1.0f);
        else               pos = fmaf((float)(row - 56), 2.0f / 47.0f, -1.0f);
        float f = pos * base;
        tabs[idx] = make_float2(cosf(f), sinf(f));
    }
}

// ---------------- fused QKV GEMM (transposed) + RMSnorm + RoPE.
// R22: 128(M) x 256(N) tile, 512 threads (8 waves, 2x4 grid), each wave
// 64x64 = acc[4][4] (R17's 0.5 LDS-reads/MFMA, 32 MFMA/step/wave) + 3-buffer
// counted-vmcnt(3) pipeline (LDS 72KB -> 2 blocks/CU = 16 waves/CU).
// Per-output K-order unchanged (bitwise-identical). bm FAST (12 consecutive
// blocks share an x-panel); head-major outputs via LDS-transpose epilogue.
__global__ __launch_bounds__(512) void gemm_qkv(const ushort* __restrict__ Ah,
                                                const ushort* __restrict__ Bh,
                                                const float2* __restrict__ tabs,
                                                const float* __restrict__ qnw,
                                                const float* __restrict__ knw,
                                                ushort* __restrict__ qbf,
                                                ushort* __restrict__ kbf,
                                                ushort* __restrict__ vbf) {
    const int K = 512, nM = 12;               // 12 M-tiles (1536/128)
    __shared__ __align__(16) char smem[73728];   // 3 x (8K A + 16K B)
#define AS_(b) ((ushort*)(smem + (b) * 24576))
#define BS_(b) ((ushort*)(smem + (b) * 24576 + 8192))
    int nwg = gridDim.x;
    int bid = blockIdx.x;
    int cpx = nwg >> 3;
    int swz = (bid & 7) * cpx + (bid >> 3);
    int bm = (swz % nM) * 128, bn = (swz / nM) * 256;   // bm fast!
    int tid = threadIdx.x;
    int lane = tid & 63, wave = tid >> 6;     // 8 waves
    int wr = wave >> 2, wc = wave & 3;        // 2(M) x 4(N) wave grid
    int fr = lane & 15, kg = lane >> 4;

    f32x4 acc[4][4];
#pragma unroll
    for (int m = 0; m < 4; ++m)
#pragma unroll
        for (int n = 0; n < 4; ++n) acc[m][n] = (f32x4){0.f, 0.f, 0.f, 0.f};

    // one K-step batch = 3 gloads/thread (A:1 of 512 chunks, B:2 of 1024)
    auto stage = [&](int buf, int k0) {
        {
            int row = tid >> 2, ch = tid & 3;
            int sl = ch ^ ((row >> 1) & 3);
            gload16(Ah + (size_t)(bm + row) * K + k0 + sl * 8, AS_(buf) + tid * 8);
        }
#pragma unroll
        for (int it = 0; it < 2; ++it) {
            int f = it * 512 + tid;
            int row = f >> 2, ch = f & 3;
            int sl = ch ^ ((row >> 1) & 3);
            gload16(Bh + (size_t)(bn + row) * K + k0 + sl * 8, BS_(buf) + f * 8);
        }
    };

    int nt = K >> 5;                          // 16 K-steps
    stage(0, 0);
    int cb = 0, nb = 1;
    int ksw = (kg ^ ((fr >> 1) & 3)) * 8;
    for (int t = 0; t < nt; ++t) {
        if (t + 1 < nt) {
            stage(nb, (t + 1) << 5);          // issue next batch (stays in flight)
            asm volatile("s_waitcnt vmcnt(3)" ::: "memory");   // current buf landed
        } else {
            asm volatile("s_waitcnt vmcnt(0)" ::: "memory");
        }
        __builtin_amdgcn_s_barrier();
        __builtin_amdgcn_sched_barrier(0);
        const ushort* Bc = BS_(cb);
        const ushort* Ac = AS_(cb);
        bf16x8 bh[4];
#pragma unroll
        for (int n = 0; n < 4; ++n)
            bh[n] = *(const bf16x8*)&Bc[(wc * 64 + n * 16 + fr) * 32 + ksw];
#pragma unroll
        for (int m = 0; m < 4; ++m) {
            bf16x8 ah = *(const bf16x8*)&Ac[(wr * 64 + m * 16 + fr) * 32 + ksw];
#pragma unroll
            for (int n = 0; n < 4; ++n)
                acc[m][n] = mfma_bf16(ah, bh[n], acc[m][n]);
        }
        cb = (cb + 1 == 3) ? 0 : cb + 1;
        nb = (nb + 1 == 3) ? 0 : nb + 1;
    }
    __syncthreads();   // waves not tail-synced; LDS reused below

    // ---- fused epilogue (staging LDS dead; wave-private 5KB transpose buf)
    int g = (bm >> 6) + wr;
    int type = g % 3;        // 0=q, 1=k, 2=v
    int h = g / 3;
    ushort* obuf = (type == 0) ? qbf : (type == 1) ? kbf : vbf;
    float qsc = (type == 0) ? 0.125f : 1.0f;
    float4 wv[4];
    if (type < 2) {
        const float* wptr = type ? knw : qnw;
#pragma unroll
        for (int m = 0; m < 4; ++m)
            wv[m] = *(const float4*)&wptr[m * 16 + kg * 4];
    }
    char* tb = smem + wave * 5120;            // 32 rows x 160B, wave-private
    size_t obase = (size_t)h * TOK + bn + wc * 64;   // head-major token base

#pragma unroll
    for (int hp = 0; hp < 2; ++hp) {
#pragma unroll
        for (int nn = 0; nn < 2; ++nn) {
            int n = hp * 2 + nn;
            int tk = bn + wc * 64 + n * 16 + fr;
            if (type == 2) {
#pragma unroll
                for (int m = 0; m < 4; ++m) {
                    ushort4 pk = {f2bf(acc[m][n][0]), f2bf(acc[m][n][1]),
                                  f2bf(acc[m][n][2]), f2bf(acc[m][n][3])};
                    *(ushort4*)(tb + (nn * 16 + fr) * 160 + (m * 16 + kg * 4) * 2) = pk;
                }
            } else {
                float s = 0.f;
#pragma unroll
                for (int m = 0; m < 4; ++m)
#pragma unroll
                    for (int i = 0; i < 4; ++i)
                        s = fmaf(acc[m][n][i], acc[m][n][i], s);
                s += __shfl_xor(s, 16);
                s += __shfl_xor(s, 32);
                float inv = rsqrtf(s * (1.0f / 64.0f) + 1e-6f);
                int t = tk / (HH * WW);
                int rem = tk % (HH * WW);
                int xx = rem / WW, yy = rem % WW;
#pragma unroll
                for (int m = 0; m < 4; ++m) {
                    float r[4];
                    const float* wm = (const float*)&wv[m];
#pragma unroll
                    for (int u = 0; u < 2; ++u) {
                        int dc0 = m * 16 + kg * 4 + 2 * u;
                        float xn0 = acc[m][n][2 * u]     * inv * wm[2 * u];
                        float xn1 = acc[m][n][2 * u + 1] * inv * wm[2 * u + 1];
                        if (dc0 < 60) {
                            int p = dc0 >> 1;
                            int tr = (p < 10) ? t * 10 + p
                                   : (p < 20) ? (8 + xx) * 10 + (p - 10)
                                              : (56 + yy) * 10 + (p - 20);
                            float2 cs = tabs[tr];
                            r[2 * u]     = fmaf(xn0, cs.x, -xn1 * cs.y);
                            r[2 * u + 1] = fmaf(xn1, cs.x,  xn0 * cs.y);
                        } else {
                            r[2 * u] = xn0;
                            r[2 * u + 1] = xn1;
                        }
                    }
                    ushort4 pk = {f2bf(r[0] * qsc), f2bf(r[1] * qsc),
                                  f2bf(r[2] * qsc), f2bf(r[3] * qsc)};
                    *(ushort4*)(tb + (nn * 16 + fr) * 160 + (m * 16 + kg * 4) * 2) = pk;
                }
            }
        }
        // readback token-per-row, store 1KB-contiguous per wave instruction.
#pragma unroll
        for (int j = 0; j < 4; ++j) {
            int row = j * 8 + (lane >> 3);            // local token 0..31
            int c16 = (lane & 7) * 16;                // 16B chunk in 128B row
            u16x8 v = *(const u16x8*)(tb + row * 160 + c16);
            size_t tok = obase + hp * 32 + row;
            *(u16x8*)(obuf + tok * 64 + (lane & 7) * 8) = v;
        }
    }
#undef AS_
#undef BS_
}

// ---------------- output GEMM: C = o @ w_out^T (non-transposed, coalesced C).
// R21 proven: 512 threads, 128x128 tile, 3-buffer counted-vmcnt(2) pipeline.
__global__ __launch_bounds__(512) void gemm_out(const ushort* __restrict__ Ah,
                                                const ushort* __restrict__ Bh,
                                                float* __restrict__ C) {
    const int N = 512, K = 512, nbx = 4;
    __shared__ __align__(16) char smem[49152];
#define AS_(b) ((ushort*)(smem + (b) * 16384))
#define BS_(b) ((ushort*)(smem + (b) * 16384 + 8192))
    int nwg = gridDim.x;
    int bid = blockIdx.x;
    int cpx = nwg >> 3;
    int swz = (bid & 7) * cpx + (bid >> 3);
    int bm = (swz / nbx) * 128, bn = (swz % nbx) * 128;
    int tid = threadIdx.x;
    int lane = tid & 63, wave = tid >> 6;
    int wr = wave >> 2, wc = wave & 3;
    int fr = lane & 15, kg = lane >> 4;

    f32x4 acc[4][2];
#pragma unroll
    for (int m = 0; m < 4; ++m)
#pragma unroll
        for (int n = 0; n < 2; ++n) acc[m][n] = (f32x4){0.f, 0.f, 0.f, 0.f};

    auto stage = [&](int buf, int k0) {
        int row = tid >> 2, ch = tid & 3;
        int sl = ch ^ ((row >> 1) & 3);
        gload16(Ah + (size_t)(bm + row) * K + k0 + sl * 8, AS_(buf) + tid * 8);
        gload16(Bh + (size_t)(bn + row) * K + k0 + sl * 8, BS_(buf) + tid * 8);
    };

    int nt = K >> 5;
    stage(0, 0);
    int cb = 0, nb = 1;
    int ksw = (kg ^ ((fr >> 1) & 3)) * 8;
    for (int t = 0; t < nt; ++t) {
        if (t + 1 < nt) {
            stage(nb, (t + 1) << 5);
            asm volatile("s_waitcnt vmcnt(2)" ::: "memory");
        } else {
            asm volatile("s_waitcnt vmcnt(0)" ::: "memory");
        }
        __builtin_amdgcn_s_barrier();
        __builtin_amdgcn_sched_barrier(0);
        const ushort* Bc = BS_(cb);
        const ushort* Ac = AS_(cb);
        bf16x8 bh[2];
#pragma unroll
        for (int n = 0; n < 2; ++n)
            bh[n] = *(const bf16x8*)&Bc[(wc * 32 + n * 16 + fr) * 32 + ksw];
#pragma unroll
        for (int m = 0; m < 4; ++m) {
            bf16x8 ah = *(const bf16x8*)&Ac[(wr * 64 + m * 16 + fr) * 32 + ksw];
#pragma unroll
            for (int n = 0; n < 2; ++n)
                acc[m][n] = mfma_bf16(ah, bh[n], acc[m][n]);
        }
        cb = (cb + 1 == 3) ? 0 : cb + 1;
        nb = (nb + 1 == 3) ? 0 : nb + 1;
    }
#pragma unroll
    for (int m = 0; m < 4; ++m) {
        int row0 = bm + wr * 64 + m * 16 + kg * 4;
#pragma unroll
        for (int n = 0; n < 2; ++n) {
            int col = bn + wc * 32 + n * 16 + fr;
#pragma unroll
            for (int i = 0; i < 4; ++i)
                C[(size_t)(row0 + i) * N + col] = acc[m][n][i];
        }
    }
#undef AS_
#undef BS_
}

// ---------------- MFMA neighborhood attention v4: ALL 4 waves in QK^T +
// softmax, per-q cross-wave exchange, setprio. Block = (2x2 patch, head).
// q/k/v HEAD-MAJOR [h][TOK][64]; output ohi [tok][512].
__global__ __launch_bounds__(256) void attn_mfma(const ushort* __restrict__ qbf,
                                                 const ushort* __restrict__ kbf,
                                                 const ushort* __restrict__ vbf,
                                                 ushort* __restrict__ ohi) {
    __shared__ __align__(16) char smem[45568];
    constexpr int Q_OFF = 0;       // [32 q][64 d] bf16, 128B rows, slot16 ^= row&7
    constexpr int K_OFF = 4096;    // [128 k][64 d] bf16, 128B rows, slot16 ^= row&7
    constexpr int V_OFF = 20480;   // [64 d][128 k] bf16, 256B rows, slot16 ^= d&7
    constexpr int P_OFF = 36864;   // [32 q][128 k] bf16, 256B rows, slot16 ^= q&7
    constexpr int XM_OFF = 45056;  // [2 qt][2 mh][16 q] f32 partial max
    constexpr int XS_OFF = 45312;  // [2 qt][2 mh][16 q] f32 partial sum

    int patch = blockIdx.x, head = blockIdx.y;
    int bi = patch / 24, bj = patch % 24;
    int x0 = bi * 2, y0 = bj * 2;
    int ubx = min(max(x0 - 1, 0), 44), uby = min(max(y0 - 1, 0), 44);
    int tid = threadIdx.x, lane = tid & 63, w = tid >> 6;
    int fr = lane & 15, kg = lane >> 4;
    size_t hbase = (size_t)head * TOK;

    // ---- stage Q (1 gload/thread, pre-swizzled source chunk)
    {
        int f = tid;
        int row = f >> 3, sp = f & 7, sl = sp ^ (row & 7);
        int t = row >> 2, px = (row >> 1) & 1, py = row & 1;
        size_t tok = ((size_t)(t * HH + x0 + px)) * WW + (y0 + py);
        gload16(qbf + (hbase + tok) * 64 + sl * 8, smem + Q_OFF + f * 16);
    }
    // ---- stage K (4 gloads/thread)
#pragma unroll
    for (int it = 0; it < 4; ++it) {
        int f = it * 256 + tid;
        int row = f >> 3, sp = f & 7, sl = sp ^ (row & 7);
        int s = row >> 4, ki = (row >> 2) & 3, kj = row & 3;
        size_t tok = ((size_t)(s * HH + ubx + ki)) * WW + (uby + kj);
        gload16(kbf + (hbase + tok) * 64 + sl * 8, smem + K_OFF + f * 16);
    }
    // ---- stage V^T from vbf: register 4x4 transpose, b64 swizzled writes
#pragma unroll
    for (int it = 0; it < 2; ++it) {
        int u = it * 256 + tid;
        int sk = u >> 4, dg = u & 15;
        int s = sk >> 2, ki = sk & 3;
        ushort4 rv[4];
#pragma unroll
        for (int kj = 0; kj < 4; ++kj) {
            size_t tok = ((size_t)(s * HH + ubx + ki)) * WW + (uby + kj);
            rv[kj] = *(const ushort4*)(vbf + (hbase + tok) * 64 + dg * 4);
        }
        const ushort* rr = (const ushort*)rv;   // rr[kj*4 + dd]
#pragma unroll
        for (int dd = 0; dd < 4; ++dd) {
            int d = dg * 4 + dd;
            ushort4 val = {rr[dd], rr[4 + dd], rr[8 + dd], rr[12 + dd]};
            *(ushort4*)(smem + V_OFF + d * 256 + ((sk * 8) ^ ((d & 7) << 4))) = val;
        }
    }
    __syncthreads();

    // ---- QK^T swapped (S^T = K * Q^T), ALL 4 waves:
    // wave w: q-tile qt = w&1, m-half mh = w>>1 (m = mh*4 .. mh*4+3)
    float* XM = (float*)(smem + XM_OFF);
    float* XS = (float*)(smem + XS_OFF);
    int qt = w & 1, mh = w >> 1;
    int q = qt * 16 + fr;        // q = t*4 + px*2 + py
    {
        bf16x8 qb[2];
#pragma unroll
        for (int ks = 0; ks < 2; ++ks)
            qb[ks] = *(const bf16x8*)(smem + Q_OFF + q * 128 +
                                      ((ks * 64 + kg * 16) ^ ((fr & 7) << 4)));
        f32x4 sc[4];
#pragma unroll
        for (int mm = 0; mm < 4; ++mm) sc[mm] = (f32x4){0.f, 0.f, 0.f, 0.f};
        __builtin_amdgcn_s_setprio(1);
#pragma unroll
        for (int mm = 0; mm < 4; ++mm) {
            int m = mh * 4 + mm;
#pragma unroll
            for (int ks = 0; ks < 2; ++ks) {
                bf16x8 a = *(const bf16x8*)(smem + K_OFF + (m * 16 + fr) * 128 +
                                            ((ks * 64 + kg * 16) ^ ((fr & 7) << 4)));
                sc[mm] = mfma_bf16(a, qb[ks], sc[mm]);
            }
        }
        __builtin_amdgcn_s_setprio(0);
        // lane holds S[k = (mh*4+mm)*16 + kg*4 + i][q]: s=m, ki=kg, kj=i
        int xq = x0 + ((q >> 1) & 1), yq = y0 + (q & 1);
        int lox = min(max(xq - 1, 0), 45) - ubx;
        int loy = min(max(yq - 1, 0), 45) - uby;
        bool vki = ((unsigned)(kg - lox)) <= 2u;
        float mx = -1e30f;
        if (vki) {
#pragma unroll
            for (int mm = 0; mm < 4; ++mm)
#pragma unroll
                for (int i = 0; i < 4; ++i)
                    if (((unsigned)(i - loy)) <= 2u) mx = fmaxf(mx, sc[mm][i]);
        }
        mx = fmaxf(mx, __shfl_xor(mx, 16));   // per-q (reduced over kg)
        mx = fmaxf(mx, __shfl_xor(mx, 32));
        if (kg == 0) XM[(qt * 2 + mh) * 16 + fr] = mx;
        __syncthreads();
        mx = fmaxf(XM[(qt * 2 + 0) * 16 + fr], XM[(qt * 2 + 1) * 16 + fr]);
        float sum = 0.f;
#pragma unroll
        for (int mm = 0; mm < 4; ++mm)
#pragma unroll
            for (int i = 0; i < 4; ++i) {
                bool v = vki && (((unsigned)(i - loy)) <= 2u);
                float e = v ? __expf(sc[mm][i] - mx) : 0.f;
                sc[mm][i] = e;
                sum += e;
            }
        sum += __shfl_xor(sum, 16);           // per-q partial sum
        sum += __shfl_xor(sum, 32);
        if (kg == 0) XS[(qt * 2 + mh) * 16 + fr] = sum;
        __syncthreads();
        float inv = 1.0f / (XS[(qt * 2 + 0) * 16 + fr] + XS[(qt * 2 + 1) * 16 + fr]);
#pragma unroll
        for (int mm = 0; mm < 4; ++mm) {
            int m = mh * 4 + mm;
            ushort4 pk = {f2bf(sc[mm][0] * inv), f2bf(sc[mm][1] * inv),
                          f2bf(sc[mm][2] * inv), f2bf(sc[mm][3] * inv)};
            *(ushort4*)(smem + P_OFF + q * 256 +
                        ((m * 32 + kg * 8) ^ ((q & 7) << 4))) = pk;
        }
    }
    __syncthreads();

    // ---- PV swapped (out^T = V^T * P^T): wave w owns d-tile w
    f32x4 ov[2];
    ov[0] = (f32x4){0.f, 0.f, 0.f, 0.f};
    ov[1] = (f32x4){0.f, 0.f, 0.f, 0.f};
    __builtin_amdgcn_s_setprio(1);
#pragma unroll
    for (int kb = 0; kb < 4; ++kb) {
        bf16x8 a = *(const bf16x8*)(smem + V_OFF + (w * 16 + fr) * 256 +
                                    ((kb * 64 + kg * 16) ^ ((fr & 7) << 4)));
#pragma unroll
        for (int nt2 = 0; nt2 < 2; ++nt2) {
            bf16x8 b = *(const bf16x8*)(smem + P_OFF + (nt2 * 16 + fr) * 256 +
                                        ((kb * 64 + kg * 16) ^ ((fr & 7) << 4)));
            ov[nt2] = mfma_bf16(a, b, ov[nt2]);
        }
    }
    __builtin_amdgcn_s_setprio(0);
    // ---- epilogue: lane holds out^T[d = w*16+kg*4+i][q = nt2*16+fr]
#pragma unroll
    for (int nt2 = 0; nt2 < 2; ++nt2) {
        int qq = nt2 * 16 + fr;
        int t = qq >> 2, px = (qq >> 1) & 1, py = qq & 1;
        size_t tok = ((size_t)(t * HH + x0 + px)) * WW + (y0 + py);
        size_t ob = tok * 512 + head * 64 + w * 16 + kg * 4;
        ushort4 hv = {f2bf(ov[nt2][0]), f2bf(ov[nt2][1]),
                      f2bf(ov[nt2][2]), f2bf(ov[nt2][3])};
        *(ushort4*)&ohi[ob] = hv;
    }
}

extern "C" void kernel_launch(void* const* d_in, const int* in_sizes, int n_in,
                              void* d_out, int out_size, void* d_ws, size_t ws_size,
                              hipStream_t stream) {
    const float* x     = (const float*)d_in[0];
    const float* w_qkv = (const float*)d_in[1];
    const float* w_out = (const float*)d_in[2];
    const float* qnw   = (const float*)d_in[3];
    const float* knw   = (const float*)d_in[4];
    float* out = (float*)d_out;
    char*  ws  = (char*)d_ws;

    const size_t TABS_B = 16384;
    const size_t WQ_B   = (size_t)1536 * 512 * 2;   // 1,572,864
    const size_t WO_B   = (size_t)512 * 512 * 2;    //   524,288

    // ws layout: tabs | wqhi | wohi | qbf | kbf | vbf | ohi  (~77.6 MB)
    float2* tabs = (float2*)ws;
    ushort* wqhi = (ushort*)(ws + TABS_B);
    ushort* wohi = wqhi + (size_t)1536 * 512;
    ushort* qbf  = (ushort*)(ws + TABS_B + WQ_B + WO_B);   // head-major [h][TOK][64]
    ushort* kbf  = qbf + (size_t)TOK * 512;
    ushort* vbf  = kbf + (size_t)TOK * 512;
    ushort* ohi  = vbf + (size_t)TOK * 512;                // [tok][512]

    // d_out: phase 1 = xhi (bf16 x, 37.7 MB); phase 2 = final fp32 out.
    ushort* xhi = (ushort*)d_out;

    init_misc<<<10245, 256, 0, stream>>>(x, xhi, w_qkv, wqhi, w_out, wohi, tabs);

    // fused: qkv^T GEMM (bf16 x from xhi) + rmsnorm + rope -> q/k/v head-major
    gemm_qkv<<<(1536 / 128) * (TOK / 256), 512, 0, stream>>>(
        wqhi, xhi, tabs, qnw, knw, qbf, kbf, vbf);
    attn_mfma<<<dim3(576, NH), 256, 0, stream>>>(qbf, kbf, vbf, ohi);
    // out = o @ w_out^T  (non-transposed, coalesced C writes)
    gemm_out<<<(TOK / 128) * (512 / 128), 512, 0, stream>>>(ohi, wohi, out);
}